// Round 1
// 265.690 us; speedup vs baseline: 1.1305x; 1.1305x over previous
//
#include <hip/hip_runtime.h>
#include <hip/hip_fp16.h>

#define H 64
#define CBS 512           // nodes per coarse bucket
#define CB_BITS 9
#define TILE 8192         // edges per partition tile
#define CAP 9216          // slab capacity per bucket
#define NSTAT 64          // BN-stats replicas (contention spreading)

typedef _Float16 f16;
typedef __attribute__((ext_vector_type(8))) _Float16 v8h;
typedef __attribute__((ext_vector_type(4))) float v4f;

// ---------------------------------------------------------------------------
// cvt_x + init fused: grid covers x conversion; block 0 also seeds slab
// cursors. (BN stats now live in replicated statsR, zeroed in repack.)
// ---------------------------------------------------------------------------
__global__ __launch_bounds__(256)
void cvt_init_kernel(const float* __restrict__ x, f16* __restrict__ xh, int total4,
                     int* __restrict__ gcursor, int CB) {
    int i = blockIdx.x * blockDim.x + threadIdx.x;
    if (blockIdx.x == 0) {
        int t = threadIdx.x;
        if (t < CB) gcursor[t * 16] = t * CAP;
    }
    if (i >= total4) return;
    float4 v = ((const float4*)x)[i];
    f16 h0 = (f16)v.x, h1 = (f16)v.y, h2 = (f16)v.z, h3 = (f16)v.w;
    ushort4 pk;
    pk.x = *(unsigned short*)&h0; pk.y = *(unsigned short*)&h1;
    pk.z = *(unsigned short*)&h2; pk.w = *(unsigned short*)&h3;
    ((ushort4*)xh)[i] = pk;
}

// ---------------------------------------------------------------------------
// LDS-staged multi-split partition into per-bucket slabs (R11-proven).
// ---------------------------------------------------------------------------
__global__ __launch_bounds__(256)
void part_staged_kernel(const int* __restrict__ ei, int* __restrict__ gcursor,
                        int* __restrict__ pairs, int E, int N, int CB) {
    __shared__ int sd[256];
    __shared__ int excl[256];
    __shared__ int gbase[256];
    __shared__ int lcur[256];
    __shared__ int stage[TILE];
    __shared__ unsigned char bin8[TILE];
    int t = threadIdx.x;
    int ntiles = (E + TILE - 1) / TILE;
    for (int tile = blockIdx.x; tile < ntiles; tile += gridDim.x) {
        int base = tile * TILE;
        int cnt = min(TILE, E - base);
        sd[t] = 0;
        __syncthreads();
        for (int i = t; i < cnt; i += 256) {
            int s = ei[base + i];
            int d = ei[E + base + i];
            if ((unsigned)s < (unsigned)N && (unsigned)d < (unsigned)N)
                atomicAdd(&sd[d >> CB_BITS], 1);
        }
        __syncthreads();
        int v = sd[t];
        __syncthreads();
        for (int off = 1; off < 256; off <<= 1) {
            int add = (t >= off) ? sd[t - off] : 0;
            __syncthreads();
            sd[t] += add;
            __syncthreads();
        }
        int ex = sd[t] - v;
        excl[t] = ex;
        lcur[t] = ex;
        if (t < CB && v > 0) gbase[t] = atomicAdd(&gcursor[t * 16], v);
        int tot = sd[255];
        __syncthreads();
        for (int i = t; i < cnt; i += 256) {
            int s = ei[base + i];
            int d = ei[E + base + i];
            if ((unsigned)s < (unsigned)N && (unsigned)d < (unsigned)N) {
                int cb = d >> CB_BITS;
                int pos = atomicAdd(&lcur[cb], 1);
                stage[pos] = s | ((d & (CBS - 1)) << 17);
                bin8[pos] = (unsigned char)cb;
            }
        }
        __syncthreads();
        for (int i = t; i < tot; i += 256) {
            int b8 = bin8[i];
            pairs[gbase[b8] + (i - excl[b8])] = stage[i];
        }
        __syncthreads();
    }
}

__global__ __launch_bounds__(256)
void scan_cb_kernel(const int* __restrict__ gcursor, int* __restrict__ gbb,
                    int* __restrict__ rowptr, int CB, int N) {
    __shared__ int sd[256];
    int t = threadIdx.x;
    int cnt = (t < CB) ? (gcursor[t * 16] - t * CAP) : 0;
    sd[t] = cnt; __syncthreads();
    for (int off = 1; off < 256; off <<= 1) {
        int add = (t >= off) ? sd[t - off] : 0;
        __syncthreads();
        sd[t] += add;
        __syncthreads();
    }
    if (t < CB) gbb[t] = sd[t] - cnt;
    if (t == 0) { gbb[CB] = sd[255]; rowptr[N] = sd[255]; }
}

__global__ __launch_bounds__(256)
void bucket_csr_kernel(const int* __restrict__ pairs, const int* __restrict__ gcursor,
                       const int* __restrict__ gbb,
                       int* __restrict__ ebuf, int* __restrict__ rowptr, int N) {
    __shared__ int hist[CBS];
    __shared__ int cur[CBS];
    __shared__ int sd[256];
    __shared__ int carry_s;
    int b = blockIdx.x;
    int t = threadIdx.x;
    int pb = b * CAP;
    int cnt = gcursor[b * 16] - pb;
    int gb = gbb[b];
    for (int i = t; i < CBS; i += 256) hist[i] = 0;
    if (t == 0) carry_s = 0;
    __syncthreads();
    for (int i = t; i < cnt; i += 256)
        atomicAdd(&hist[(pairs[pb + i] >> 17) & (CBS - 1)], 1);
    __syncthreads();
    for (int start = 0; start < CBS; start += 256) {
        int v = hist[start + t];
        sd[t] = v; __syncthreads();
        for (int off = 1; off < 256; off <<= 1) {
            int add = (t >= off) ? sd[t - off] : 0;
            __syncthreads();
            sd[t] += add;
            __syncthreads();
        }
        int ex = sd[t] - v + carry_s;
        cur[start + t] = ex;
        int node = b * CBS + start + t;
        if (node < N) rowptr[node] = gb + ex;
        __syncthreads();
        if (t == 0) carry_s += sd[255];
        __syncthreads();
    }
    for (int i = t; i < cnt; i += 256) {
        int p = pairs[pb + i];
        int pos = atomicAdd(&cur[(p >> 17) & (CBS - 1)], 1);
        ebuf[gb + pos] = p & 0x1FFFF;
    }
}

// ---------------------------------------------------------------------------
// Repack weights into fp16 MFMA B-frag order + compute folded head inline:
//   Wf = W2b@LW (computed per-element here), bf = b2b@LW + LB.
// Also zeroes the replicated BN-stats slab (runs after bucket_csr which is
// the last reader of the pairs slab statsR aliases).
// ---------------------------------------------------------------------------
__global__ void repack_kernel(const float* __restrict__ W1a, const float* __restrict__ W1b,
                              const float* __restrict__ W2a, const float* __restrict__ W2b,
                              const float* __restrict__ B2b, const float* __restrict__ LW,
                              const float* __restrict__ LB,
                              f16* __restrict__ pk1a, f16* __restrict__ pk1b,
                              f16* __restrict__ pk2a, f16* __restrict__ pkf,
                              float* __restrict__ bf, float* __restrict__ statsR) {
    int t = blockIdx.x * blockDim.x + threadIdx.x;
    if (t < NSTAT * 128) statsR[t] = 0.f;
    if (t < 12288) {
        int m = t >> 12;
        int e = t & 4095;
        int j = e & 7, lane = (e >> 3) & 63, ks = (e >> 9) & 1, nt = e >> 10;
        int row = ks * 32 + ((lane >> 4) & 3) * 8 + j;
        int col = nt * 16 + (lane & 15);
        const float* W = (m == 0) ? W1a : (m == 1) ? W1b : W2a;
        f16* P = (m == 0) ? pk1a : (m == 1) ? pk1b : pk2a;
        P[e] = (f16)W[row * 64 + col];
    } else if (t < 13312) {
        int e = t - 12288;
        int j = e & 7, lane = (e >> 3) & 63, ks = e >> 9;
        int row = ks * 32 + ((lane >> 4) & 3) * 8 + j;
        int col = lane & 15;
        float a = 0.f;
        if (col < 10)
            for (int m = 0; m < H; ++m) a = fmaf(W2b[row * 64 + m], LW[m * 10 + col], a);
        pkf[e] = (f16)a;
    } else if (t < 13322) {
        int c = t - 13312;
        float a = LB[c];
        for (int m = 0; m < H; ++m) a = fmaf(B2b[m], LW[m * 10 + c], a);
        bf[c] = a;
    }
}

// ---------------------------------------------------------------------------
// Layer-1 gather (R13 shape, ILP deepened to 16): wave per node, lane=feature.
// ---------------------------------------------------------------------------
__global__ __launch_bounds__(256)
void gather1_kernel(const f16* __restrict__ xh, const int* __restrict__ rowptr,
                    const int* __restrict__ ebuf, f16* __restrict__ bufA, int N) {
    int wid = (int)(((long long)blockIdx.x * blockDim.x + threadIdx.x) >> 6);
    int lane = threadIdx.x & 63;
    if (wid >= N) return;
    int p0 = __builtin_amdgcn_readfirstlane(rowptr[wid]);
    int pe = __builtin_amdgcn_readfirstlane(rowptr[wid + 1]);
    float acc = (float)xh[((long long)wid << 6) + lane];
    int p = p0;
    for (; p + 16 <= pe; p += 16) {
        float v[16];
#pragma unroll
        for (int q = 0; q < 16; ++q)
            v[q] = (float)xh[((long long)ebuf[p + q] << 6) + lane];
        float s0 = ((v[0] + v[1]) + (v[2] + v[3])) + ((v[4] + v[5]) + (v[6] + v[7]));
        float s1 = ((v[8] + v[9]) + (v[10] + v[11])) + ((v[12] + v[13]) + (v[14] + v[15]));
        acc += s0 + s1;
    }
    if (p + 8 <= pe) {
        float v0 = (float)xh[((long long)ebuf[p + 0] << 6) + lane];
        float v1 = (float)xh[((long long)ebuf[p + 1] << 6) + lane];
        float v2 = (float)xh[((long long)ebuf[p + 2] << 6) + lane];
        float v3 = (float)xh[((long long)ebuf[p + 3] << 6) + lane];
        float v4 = (float)xh[((long long)ebuf[p + 4] << 6) + lane];
        float v5 = (float)xh[((long long)ebuf[p + 5] << 6) + lane];
        float v6 = (float)xh[((long long)ebuf[p + 6] << 6) + lane];
        float v7 = (float)xh[((long long)ebuf[p + 7] << 6) + lane];
        acc += ((v0 + v1) + (v2 + v3)) + ((v4 + v5) + (v6 + v7));
        p += 8;
    }
    for (; p < pe; ++p) acc += (float)xh[((long long)ebuf[p] << 6) + lane];
    bufA[((long long)wid << 6) + lane] = (f16)acc;
}

// ---------------------------------------------------------------------------
// Layer-2 gather (R13 shape, ILP 16) with self term and full folded BN.
// ---------------------------------------------------------------------------
__global__ __launch_bounds__(256)
void gather2_kernel(const f16* __restrict__ h1p, const float* __restrict__ scale,
                    const float* __restrict__ shiftv, const int* __restrict__ rowptr,
                    const int* __restrict__ ebuf, f16* __restrict__ bufC, int N) {
    int wid = (int)(((long long)blockIdx.x * blockDim.x + threadIdx.x) >> 6);
    int lane = threadIdx.x & 63;
    if (wid >= N) return;
    int p0 = __builtin_amdgcn_readfirstlane(rowptr[wid]);
    int pe = __builtin_amdgcn_readfirstlane(rowptr[wid + 1]);
    float acc = (float)h1p[((long long)wid << 6) + lane];   // self
    int p = p0;
    for (; p + 16 <= pe; p += 16) {
        float v[16];
#pragma unroll
        for (int q = 0; q < 16; ++q)
            v[q] = (float)h1p[((long long)ebuf[p + q] << 6) + lane];
        float s0 = ((v[0] + v[1]) + (v[2] + v[3])) + ((v[4] + v[5]) + (v[6] + v[7]));
        float s1 = ((v[8] + v[9]) + (v[10] + v[11])) + ((v[12] + v[13]) + (v[14] + v[15]));
        acc += s0 + s1;
    }
    if (p + 8 <= pe) {
        float v0 = (float)h1p[((long long)ebuf[p + 0] << 6) + lane];
        float v1 = (float)h1p[((long long)ebuf[p + 1] << 6) + lane];
        float v2 = (float)h1p[((long long)ebuf[p + 2] << 6) + lane];
        float v3 = (float)h1p[((long long)ebuf[p + 3] << 6) + lane];
        float v4 = (float)h1p[((long long)ebuf[p + 4] << 6) + lane];
        float v5 = (float)h1p[((long long)ebuf[p + 5] << 6) + lane];
        float v6 = (float)h1p[((long long)ebuf[p + 6] << 6) + lane];
        float v7 = (float)h1p[((long long)ebuf[p + 7] << 6) + lane];
        acc += ((v0 + v1) + (v2 + v3)) + ((v4 + v5) + (v6 + v7));
        p += 8;
    }
    for (; p < pe; ++p) acc += (float)h1p[((long long)ebuf[p] << 6) + lane];
    float degp1 = (float)(pe - p0 + 1);
    bufC[((long long)wid << 6) + lane] = (f16)(acc * scale[lane] + degp1 * shiftv[lane]);
}

// ---------------------------------------------------------------------------
// MFMA MLP layer 1 + fused BN stats. Stats atomics go to one of NSTAT
// replicas (blockIdx & 63) — spreads the same-address RMW chain that
// serialized the whole dispatch (49 µs at 1% MfmaUtil).
// ---------------------------------------------------------------------------
__global__ __launch_bounds__(256)
void mlp1_kernel(const f16* __restrict__ bufA, f16* __restrict__ h1p,
                 const f16* __restrict__ pk1a, const f16* __restrict__ pk1b,
                 const float* __restrict__ B1a, const float* __restrict__ B1b,
                 float* __restrict__ statsR, int N) {
    __shared__ f16 Su[4][16 * 72];
    __shared__ f16 Sh[4][16 * 72];
    __shared__ float red[2][4][64];
    int t = threadIdx.x, wv = t >> 6, lane = t & 63;
    int quad = lane >> 4, r16 = lane & 15;
    int node0 = blockIdx.x * 64 + wv * 16;
    int nodeA = node0 + r16;

    v8h a0 = {}, a1 = {};
    if (nodeA < N) {
        a0 = *(const v8h*)(bufA + (size_t)nodeA * 64 + quad * 8);
        a1 = *(const v8h*)(bufA + (size_t)nodeA * 64 + 32 + quad * 8);
    }
#pragma unroll
    for (int nt = 0; nt < 4; ++nt) {
        v8h b0 = *(const v8h*)(pk1a + (((nt * 2 + 0) * 64 + lane) << 3));
        v8h b1 = *(const v8h*)(pk1a + (((nt * 2 + 1) * 64 + lane) << 3));
        v4f c = {0.f, 0.f, 0.f, 0.f};
        c = __builtin_amdgcn_mfma_f32_16x16x32_f16(a0, b0, c, 0, 0, 0);
        c = __builtin_amdgcn_mfma_f32_16x16x32_f16(a1, b1, c, 0, 0, 0);
        float bias = B1a[nt * 16 + r16];
#pragma unroll
        for (int reg = 0; reg < 4; ++reg)
            Su[wv][(quad * 4 + reg) * 72 + nt * 16 + r16] = (f16)fmaxf(c[reg] + bias, 0.f);
    }
    __syncthreads();
    v8h u0 = *(const v8h*)(&Su[wv][r16 * 72 + quad * 8]);
    v8h u1 = *(const v8h*)(&Su[wv][r16 * 72 + 32 + quad * 8]);
#pragma unroll
    for (int nt = 0; nt < 4; ++nt) {
        v8h b0 = *(const v8h*)(pk1b + (((nt * 2 + 0) * 64 + lane) << 3));
        v8h b1 = *(const v8h*)(pk1b + (((nt * 2 + 1) * 64 + lane) << 3));
        v4f c = {0.f, 0.f, 0.f, 0.f};
        c = __builtin_amdgcn_mfma_f32_16x16x32_f16(u0, b0, c, 0, 0, 0);
        c = __builtin_amdgcn_mfma_f32_16x16x32_f16(u1, b1, c, 0, 0, 0);
        float bias = B1b[nt * 16 + r16];
#pragma unroll
        for (int reg = 0; reg < 4; ++reg) {
            int row = quad * 4 + reg;
            bool valid = (node0 + row) < N;
            Sh[wv][row * 72 + nt * 16 + r16] = valid ? (f16)(c[reg] + bias) : (f16)0;
        }
    }
    __syncthreads();
    for (int i = lane; i < 1024; i += 64) {
        int row = i >> 6, col = i & 63;
        int node = node0 + row;
        if (node < N) h1p[(size_t)node * 64 + col] = Sh[wv][row * 72 + col];
    }
    float s = 0.f, s2 = 0.f;
#pragma unroll
    for (int row = 0; row < 16; ++row) {
        float v = (float)Sh[wv][row * 72 + lane];
        s += v;
        s2 = fmaf(v, v, s2);
    }
    red[0][wv][lane] = s;
    red[1][wv][lane] = s2;
    __syncthreads();
    if (wv == 0) {
        float ts  = (red[0][0][lane] + red[0][1][lane]) + (red[0][2][lane] + red[0][3][lane]);
        float ts2 = (red[1][0][lane] + red[1][1][lane]) + (red[1][2][lane] + red[1][3][lane]);
        float* st = statsR + (size_t)(blockIdx.x & (NSTAT - 1)) * 128;
        unsafeAtomicAdd(&st[lane], ts);
        unsafeAtomicAdd(&st[64 + lane], ts2);
    }
}

__global__ void bn_finalize_kernel(const float* __restrict__ statsR,
                                   const float* __restrict__ gamma,
                                   const float* __restrict__ beta,
                                   float* __restrict__ scale, float* __restrict__ shiftv, float n) {
    int f = threadIdx.x;
    if (f >= H) return;
    float s = 0.f, s2 = 0.f;
    for (int r = 0; r < NSTAT; ++r) {
        s  += statsR[r * 128 + f];
        s2 += statsR[r * 128 + 64 + f];
    }
    float mean = s / n;
    float var = s2 / n - mean * mean;   // biased, matches jnp.var
    var = fmaxf(var, 0.f);
    float sc = gamma[f] * rsqrtf(var + 1e-5f);
    scale[f] = sc;
    shiftv[f] = beta[f] - mean * sc;
}

// ---------------------------------------------------------------------------
// MFMA MLP layer 2 + folded head (R13-proven).
// ---------------------------------------------------------------------------
__global__ __launch_bounds__(256)
void mlp2_kernel(const f16* __restrict__ bufC,
                 const f16* __restrict__ pk2a, const f16* __restrict__ pkf,
                 const float* __restrict__ B2a, const float* __restrict__ bf,
                 float* __restrict__ out, int N) {
    __shared__ f16 Su[4][16 * 72];
    int t = threadIdx.x, wv = t >> 6, lane = t & 63;
    int quad = lane >> 4, r16 = lane & 15;
    int node0 = blockIdx.x * 64 + wv * 16;
    int nodeA = node0 + r16;

    v8h a0 = {}, a1 = {};
    if (nodeA < N) {
        a0 = *(const v8h*)(bufC + (size_t)nodeA * 64 + quad * 8);
        a1 = *(const v8h*)(bufC + (size_t)nodeA * 64 + 32 + quad * 8);
    }
#pragma unroll
    for (int nt = 0; nt < 4; ++nt) {
        v8h b0 = *(const v8h*)(pk2a + (((nt * 2 + 0) * 64 + lane) << 3));
        v8h b1 = *(const v8h*)(pk2a + (((nt * 2 + 1) * 64 + lane) << 3));
        v4f c = {0.f, 0.f, 0.f, 0.f};
        c = __builtin_amdgcn_mfma_f32_16x16x32_f16(a0, b0, c, 0, 0, 0);
        c = __builtin_amdgcn_mfma_f32_16x16x32_f16(a1, b1, c, 0, 0, 0);
        float bias = B2a[nt * 16 + r16];
#pragma unroll
        for (int reg = 0; reg < 4; ++reg)
            Su[wv][(quad * 4 + reg) * 72 + nt * 16 + r16] = (f16)fmaxf(c[reg] + bias, 0.f);
    }
    __syncthreads();
    v8h u0 = *(const v8h*)(&Su[wv][r16 * 72 + quad * 8]);
    v8h u1 = *(const v8h*)(&Su[wv][r16 * 72 + 32 + quad * 8]);
    v8h b0 = *(const v8h*)(pkf + ((0 * 64 + lane) << 3));
    v8h b1 = *(const v8h*)(pkf + ((1 * 64 + lane) << 3));
    v4f c = {0.f, 0.f, 0.f, 0.f};
    c = __builtin_amdgcn_mfma_f32_16x16x32_f16(u0, b0, c, 0, 0, 0);
    c = __builtin_amdgcn_mfma_f32_16x16x32_f16(u1, b1, c, 0, 0, 0);
    if (r16 < 10) {
        float bias = bf[r16];
#pragma unroll
        for (int reg = 0; reg < 4; ++reg) {
            int node = node0 + quad * 4 + reg;
            if (node < N) out[(size_t)node * 10 + r16] = c[reg] + bias;
        }
    }
}

extern "C" void kernel_launch(void* const* d_in, const int* in_sizes, int n_in,
                              void* d_out, int out_size, void* d_ws, size_t ws_size,
                              hipStream_t stream) {
    const float* x    = (const float*)d_in[0];
    const int*   ei   = (const int*)d_in[1];
    const float* w1a  = (const float*)d_in[2];
    const float* b1a  = (const float*)d_in[3];
    const float* w1b  = (const float*)d_in[4];
    const float* b1b  = (const float*)d_in[5];
    const float* bng  = (const float*)d_in[6];
    const float* bnb  = (const float*)d_in[7];
    const float* w2a  = (const float*)d_in[8];
    const float* b2a  = (const float*)d_in[9];
    const float* w2b  = (const float*)d_in[10];
    const float* b2b  = (const float*)d_in[11];
    const float* linw = (const float*)d_in[12];
    const float* linb = (const float*)d_in[13];

    int N = in_sizes[0] / H;       // 100000
    int E = in_sizes[1] / 2;       // 1600000
    int CB = (N + CBS - 1) / CBS;  // 196 coarse buckets

    // ---- workspace layout ----
    size_t NH = (size_t)N * H;
    char*  wsb    = (char*)d_ws;
    f16*   xh     = (f16*)wsb;                           // NH fp16
    f16*   bufA   = (f16*)(wsb + NH * 2);                // NH fp16 (agg1 -> h1p in place)
    f16*   bufC   = (f16*)(wsb + NH * 4);                // NH fp16
    float* stats  = (float*)(wsb + NH * 6);              // 128 (legacy, unused)
    float* scale  = stats + 128;                         // 64
    float* shiftv = stats + 192;                         // 64
    float* bf     = stats + 256;                         // 16
    f16*   pk1a   = (f16*)(bf + 16);                     // 4096 (16B-aligned)
    f16*   pk1b   = pk1a + 4096;
    f16*   pk2a   = pk1b + 4096;
    f16*   pkf    = pk2a + 4096;                         // 1024
    int*   gcursor= (int*)(pkf + 1024);                  // 256*16
    int*   gbb    = gcursor + 256 * 16;                  // CB+1
    int*   rowptr = gbb + 257;                           // N+1
    int*   ebuf   = rowptr + (N + 1);                    // E
    int*   pairs  = ebuf + E;                            // CB*CAP slab
    float* statsR = (float*)pairs;                       // NSTAT*128 floats, aliases
                                                         // pairs (dead after bucket_csr)

    int ntiles = (E + TILE - 1) / TILE;

    cvt_init_kernel<<<(int)((NH / 4 + 255) / 256), 256, 0, stream>>>(
        x, xh, (int)(NH / 4), gcursor, CB);
    part_staged_kernel<<<ntiles, 256, 0, stream>>>(ei, gcursor, pairs, E, N, CB);
    scan_cb_kernel<<<1, 256, 0, stream>>>(gcursor, gbb, rowptr, CB, N);
    bucket_csr_kernel<<<CB, 256, 0, stream>>>(pairs, gcursor, gbb, ebuf, rowptr, N);
    repack_kernel<<<(13322 + 255) / 256, 256, 0, stream>>>(
        w1a, w1b, w2a, w2b, b2b, linw, linb, pk1a, pk1b, pk2a, pkf, bf, statsR);

    int gblocks = (int)(((long long)N * 64 + 255) / 256);
    int mblocks = (N + 63) / 64;
    gather1_kernel<<<gblocks, 256, 0, stream>>>(xh, rowptr, ebuf, bufA, N);
    mlp1_kernel<<<mblocks, 256, 0, stream>>>(bufA, bufA, pk1a, pk1b, b1a, b1b, statsR, N);
    bn_finalize_kernel<<<1, 64, 0, stream>>>(statsR, bng, bnb, scale, shiftv, (float)N);

    gather2_kernel<<<gblocks, 256, 0, stream>>>(bufA, scale, shiftv, rowptr, ebuf, bufC, N);
    mlp2_kernel<<<mblocks, 256, 0, stream>>>(bufC, pk2a, pkf, b2a, bf, (float*)d_out, N);
}

// Round 2
// 247.909 us; speedup vs baseline: 1.2116x; 1.0717x over previous
//
#include <hip/hip_runtime.h>
#include <hip/hip_fp16.h>

#define H 64
#define CBS 512           // nodes per coarse bucket
#define CB_BITS 9
#define TILE 8192         // edges per partition tile
#define CAP 9216          // slab capacity per bucket
#define NSTAT 64          // BN-stats replicas (contention spreading)

typedef _Float16 f16;
typedef __attribute__((ext_vector_type(8))) _Float16 v8h;
typedef __attribute__((ext_vector_type(4))) float v4f;

// ---------------------------------------------------------------------------
// cvt_x + init fused: grid covers x conversion; block 0 also seeds slab
// cursors. (BN stats live in replicated statsR, zeroed in repack.)
// ---------------------------------------------------------------------------
__global__ __launch_bounds__(256)
void cvt_init_kernel(const float* __restrict__ x, f16* __restrict__ xh, int total4,
                     int* __restrict__ gcursor, int CB) {
    int i = blockIdx.x * blockDim.x + threadIdx.x;
    if (blockIdx.x == 0) {
        int t = threadIdx.x;
        if (t < CB) gcursor[t * 16] = t * CAP;
    }
    if (i >= total4) return;
    float4 v = ((const float4*)x)[i];
    f16 h0 = (f16)v.x, h1 = (f16)v.y, h2 = (f16)v.z, h3 = (f16)v.w;
    ushort4 pk;
    pk.x = *(unsigned short*)&h0; pk.y = *(unsigned short*)&h1;
    pk.z = *(unsigned short*)&h2; pk.w = *(unsigned short*)&h3;
    ((ushort4*)xh)[i] = pk;
}

// ---------------------------------------------------------------------------
// LDS-staged multi-split partition into per-bucket slabs (R11-proven).
// ---------------------------------------------------------------------------
__global__ __launch_bounds__(256)
void part_staged_kernel(const int* __restrict__ ei, int* __restrict__ gcursor,
                        int* __restrict__ pairs, int E, int N, int CB) {
    __shared__ int sd[256];
    __shared__ int excl[256];
    __shared__ int gbase[256];
    __shared__ int lcur[256];
    __shared__ int stage[TILE];
    __shared__ unsigned char bin8[TILE];
    int t = threadIdx.x;
    int ntiles = (E + TILE - 1) / TILE;
    for (int tile = blockIdx.x; tile < ntiles; tile += gridDim.x) {
        int base = tile * TILE;
        int cnt = min(TILE, E - base);
        sd[t] = 0;
        __syncthreads();
        for (int i = t; i < cnt; i += 256) {
            int s = ei[base + i];
            int d = ei[E + base + i];
            if ((unsigned)s < (unsigned)N && (unsigned)d < (unsigned)N)
                atomicAdd(&sd[d >> CB_BITS], 1);
        }
        __syncthreads();
        int v = sd[t];
        __syncthreads();
        for (int off = 1; off < 256; off <<= 1) {
            int add = (t >= off) ? sd[t - off] : 0;
            __syncthreads();
            sd[t] += add;
            __syncthreads();
        }
        int ex = sd[t] - v;
        excl[t] = ex;
        lcur[t] = ex;
        if (t < CB && v > 0) gbase[t] = atomicAdd(&gcursor[t * 16], v);
        int tot = sd[255];
        __syncthreads();
        for (int i = t; i < cnt; i += 256) {
            int s = ei[base + i];
            int d = ei[E + base + i];
            if ((unsigned)s < (unsigned)N && (unsigned)d < (unsigned)N) {
                int cb = d >> CB_BITS;
                int pos = atomicAdd(&lcur[cb], 1);
                stage[pos] = s | ((d & (CBS - 1)) << 17);
                bin8[pos] = (unsigned char)cb;
            }
        }
        __syncthreads();
        for (int i = t; i < tot; i += 256) {
            int b8 = bin8[i];
            pairs[gbase[b8] + (i - excl[b8])] = stage[i];
        }
        __syncthreads();
    }
}

__global__ __launch_bounds__(256)
void scan_cb_kernel(const int* __restrict__ gcursor, int* __restrict__ gbb,
                    int* __restrict__ rowptr, int CB, int N) {
    __shared__ int sd[256];
    int t = threadIdx.x;
    int cnt = (t < CB) ? (gcursor[t * 16] - t * CAP) : 0;
    sd[t] = cnt; __syncthreads();
    for (int off = 1; off < 256; off <<= 1) {
        int add = (t >= off) ? sd[t - off] : 0;
        __syncthreads();
        sd[t] += add;
        __syncthreads();
    }
    if (t < CB) gbb[t] = sd[t] - cnt;
    if (t == 0) { gbb[CB] = sd[255]; rowptr[N] = sd[255]; }
}

__global__ __launch_bounds__(256)
void bucket_csr_kernel(const int* __restrict__ pairs, const int* __restrict__ gcursor,
                       const int* __restrict__ gbb,
                       int* __restrict__ ebuf, int* __restrict__ rowptr, int N) {
    __shared__ int hist[CBS];
    __shared__ int cur[CBS];
    __shared__ int sd[256];
    __shared__ int carry_s;
    int b = blockIdx.x;
    int t = threadIdx.x;
    int pb = b * CAP;
    int cnt = gcursor[b * 16] - pb;
    int gb = gbb[b];
    for (int i = t; i < CBS; i += 256) hist[i] = 0;
    if (t == 0) carry_s = 0;
    __syncthreads();
    for (int i = t; i < cnt; i += 256)
        atomicAdd(&hist[(pairs[pb + i] >> 17) & (CBS - 1)], 1);
    __syncthreads();
    for (int start = 0; start < CBS; start += 256) {
        int v = hist[start + t];
        sd[t] = v; __syncthreads();
        for (int off = 1; off < 256; off <<= 1) {
            int add = (t >= off) ? sd[t - off] : 0;
            __syncthreads();
            sd[t] += add;
            __syncthreads();
        }
        int ex = sd[t] - v + carry_s;
        cur[start + t] = ex;
        int node = b * CBS + start + t;
        if (node < N) rowptr[node] = gb + ex;
        __syncthreads();
        if (t == 0) carry_s += sd[255];
        __syncthreads();
    }
    for (int i = t; i < cnt; i += 256) {
        int p = pairs[pb + i];
        int pos = atomicAdd(&cur[(p >> 17) & (CBS - 1)], 1);
        ebuf[gb + pos] = p & 0x1FFFF;
    }
}

// ---------------------------------------------------------------------------
// Repack weights into fp16 MFMA B-frag order + folded head; zero statsR.
// ---------------------------------------------------------------------------
__global__ void repack_kernel(const float* __restrict__ W1a, const float* __restrict__ W1b,
                              const float* __restrict__ W2a, const float* __restrict__ W2b,
                              const float* __restrict__ B2b, const float* __restrict__ LW,
                              const float* __restrict__ LB,
                              f16* __restrict__ pk1a, f16* __restrict__ pk1b,
                              f16* __restrict__ pk2a, f16* __restrict__ pkf,
                              float* __restrict__ bf, float* __restrict__ statsR) {
    int t = blockIdx.x * blockDim.x + threadIdx.x;
    if (t < NSTAT * 128) statsR[t] = 0.f;
    if (t < 12288) {
        int m = t >> 12;
        int e = t & 4095;
        int j = e & 7, lane = (e >> 3) & 63, ks = (e >> 9) & 1, nt = e >> 10;
        int row = ks * 32 + ((lane >> 4) & 3) * 8 + j;
        int col = nt * 16 + (lane & 15);
        const float* W = (m == 0) ? W1a : (m == 1) ? W1b : W2a;
        f16* P = (m == 0) ? pk1a : (m == 1) ? pk1b : pk2a;
        P[e] = (f16)W[row * 64 + col];
    } else if (t < 13312) {
        int e = t - 12288;
        int j = e & 7, lane = (e >> 3) & 63, ks = e >> 9;
        int row = ks * 32 + ((lane >> 4) & 3) * 8 + j;
        int col = lane & 15;
        float a = 0.f;
        if (col < 10)
            for (int m = 0; m < H; ++m) a = fmaf(W2b[row * 64 + m], LW[m * 10 + col], a);
        pkf[e] = (f16)a;
    } else if (t < 13322) {
        int c = t - 13312;
        float a = LB[c];
        for (int m = 0; m < H; ++m) a = fmaf(B2b[m], LW[m * 10 + c], a);
        bf[c] = a;
    }
}

// ---------------------------------------------------------------------------
// Layer-1 gather, TA-optimized: 8 nodes per wave, 8 lanes per row, 16B/lane
// dwordx4 gathers (1 KB / instruction, 8 edges) instead of 2B/lane ushort
// (128 B / instruction, 1 edge). Edge indices loaded unconditionally
// (clamped) BEFORE the predicated gathers so vmcnt doesn't serialize.
// ---------------------------------------------------------------------------
__global__ __launch_bounds__(256)
void gather1_kernel(const f16* __restrict__ xh, const int* __restrict__ rowptr,
                    const int* __restrict__ ebuf, f16* __restrict__ bufA,
                    int N, int Em1) {
    int wid = (int)(((long long)blockIdx.x * blockDim.x + threadIdx.x) >> 6);
    int lane = threadIdx.x & 63;
    int g = lane >> 3, fl = lane & 7;      // node-group, feature-lane
    int node = wid * 8 + g;
    bool vn = node < N;
    int p0 = 0, deg = 0;
    if (vn) {
        p0 = rowptr[node];
        deg = rowptr[node + 1] - p0;
    }
    int m = deg;
    m = max(m, __shfl_xor(m, 8));
    m = max(m, __shfl_xor(m, 16));
    m = max(m, __shfl_xor(m, 32));

    float a[8];
    {
        v8h s = {};
        if (vn) s = *(const v8h*)(xh + ((size_t)node << 6) + fl * 8);
#pragma unroll
        for (int j = 0; j < 8; ++j) a[j] = (float)s[j];
    }
    for (int k = 0; k < m; k += 4) {
        int idx[4];
#pragma unroll
        for (int q = 0; q < 4; ++q)
            idx[q] = ebuf[min(p0 + k + q, Em1)];
#pragma unroll
        for (int q = 0; q < 4; ++q) {
            if (k + q < deg) {
                v8h v = *(const v8h*)(xh + ((size_t)idx[q] << 6) + fl * 8);
#pragma unroll
                for (int j = 0; j < 8; ++j) a[j] += (float)v[j];
            }
        }
    }
    if (vn) {
        v8h o;
#pragma unroll
        for (int j = 0; j < 8; ++j) o[j] = (f16)a[j];
        *(v8h*)(bufA + ((size_t)node << 6) + fl * 8) = o;
    }
}

// ---------------------------------------------------------------------------
// Layer-2 gather, same TA-optimized shape, with self term + folded BN.
// ---------------------------------------------------------------------------
__global__ __launch_bounds__(256)
void gather2_kernel(const f16* __restrict__ h1p, const float* __restrict__ scale,
                    const float* __restrict__ shiftv, const int* __restrict__ rowptr,
                    const int* __restrict__ ebuf, f16* __restrict__ bufC,
                    int N, int Em1) {
    int wid = (int)(((long long)blockIdx.x * blockDim.x + threadIdx.x) >> 6);
    int lane = threadIdx.x & 63;
    int g = lane >> 3, fl = lane & 7;
    int node = wid * 8 + g;
    bool vn = node < N;
    int p0 = 0, deg = 0;
    if (vn) {
        p0 = rowptr[node];
        deg = rowptr[node + 1] - p0;
    }
    int m = deg;
    m = max(m, __shfl_xor(m, 8));
    m = max(m, __shfl_xor(m, 16));
    m = max(m, __shfl_xor(m, 32));

    float a[8];
    {
        v8h s = {};
        if (vn) s = *(const v8h*)(h1p + ((size_t)node << 6) + fl * 8);
#pragma unroll
        for (int j = 0; j < 8; ++j) a[j] = (float)s[j];
    }
    for (int k = 0; k < m; k += 4) {
        int idx[4];
#pragma unroll
        for (int q = 0; q < 4; ++q)
            idx[q] = ebuf[min(p0 + k + q, Em1)];
#pragma unroll
        for (int q = 0; q < 4; ++q) {
            if (k + q < deg) {
                v8h v = *(const v8h*)(h1p + ((size_t)idx[q] << 6) + fl * 8);
#pragma unroll
                for (int j = 0; j < 8; ++j) a[j] += (float)v[j];
            }
        }
    }
    if (vn) {
        float4 sc0 = *(const float4*)(scale + fl * 8);
        float4 sc1 = *(const float4*)(scale + fl * 8 + 4);
        float4 sh0 = *(const float4*)(shiftv + fl * 8);
        float4 sh1 = *(const float4*)(shiftv + fl * 8 + 4);
        float degp1 = (float)(deg + 1);
        float sc[8] = {sc0.x, sc0.y, sc0.z, sc0.w, sc1.x, sc1.y, sc1.z, sc1.w};
        float sh[8] = {sh0.x, sh0.y, sh0.z, sh0.w, sh1.x, sh1.y, sh1.z, sh1.w};
        v8h o;
#pragma unroll
        for (int j = 0; j < 8; ++j) o[j] = (f16)(a[j] * sc[j] + degp1 * sh[j]);
        *(v8h*)(bufC + ((size_t)node << 6) + fl * 8) = o;
    }
}

// ---------------------------------------------------------------------------
// MFMA MLP layer 1 + fused BN stats into replicated accumulators.
// ---------------------------------------------------------------------------
__global__ __launch_bounds__(256)
void mlp1_kernel(const f16* __restrict__ bufA, f16* __restrict__ h1p,
                 const f16* __restrict__ pk1a, const f16* __restrict__ pk1b,
                 const float* __restrict__ B1a, const float* __restrict__ B1b,
                 float* __restrict__ statsR, int N) {
    __shared__ f16 Su[4][16 * 72];
    __shared__ f16 Sh[4][16 * 72];
    __shared__ float red[2][4][64];
    int t = threadIdx.x, wv = t >> 6, lane = t & 63;
    int quad = lane >> 4, r16 = lane & 15;
    int node0 = blockIdx.x * 64 + wv * 16;
    int nodeA = node0 + r16;

    v8h a0 = {}, a1 = {};
    if (nodeA < N) {
        a0 = *(const v8h*)(bufA + (size_t)nodeA * 64 + quad * 8);
        a1 = *(const v8h*)(bufA + (size_t)nodeA * 64 + 32 + quad * 8);
    }
#pragma unroll
    for (int nt = 0; nt < 4; ++nt) {
        v8h b0 = *(const v8h*)(pk1a + (((nt * 2 + 0) * 64 + lane) << 3));
        v8h b1 = *(const v8h*)(pk1a + (((nt * 2 + 1) * 64 + lane) << 3));
        v4f c = {0.f, 0.f, 0.f, 0.f};
        c = __builtin_amdgcn_mfma_f32_16x16x32_f16(a0, b0, c, 0, 0, 0);
        c = __builtin_amdgcn_mfma_f32_16x16x32_f16(a1, b1, c, 0, 0, 0);
        float bias = B1a[nt * 16 + r16];
#pragma unroll
        for (int reg = 0; reg < 4; ++reg)
            Su[wv][(quad * 4 + reg) * 72 + nt * 16 + r16] = (f16)fmaxf(c[reg] + bias, 0.f);
    }
    __syncthreads();
    v8h u0 = *(const v8h*)(&Su[wv][r16 * 72 + quad * 8]);
    v8h u1 = *(const v8h*)(&Su[wv][r16 * 72 + 32 + quad * 8]);
#pragma unroll
    for (int nt = 0; nt < 4; ++nt) {
        v8h b0 = *(const v8h*)(pk1b + (((nt * 2 + 0) * 64 + lane) << 3));
        v8h b1 = *(const v8h*)(pk1b + (((nt * 2 + 1) * 64 + lane) << 3));
        v4f c = {0.f, 0.f, 0.f, 0.f};
        c = __builtin_amdgcn_mfma_f32_16x16x32_f16(u0, b0, c, 0, 0, 0);
        c = __builtin_amdgcn_mfma_f32_16x16x32_f16(u1, b1, c, 0, 0, 0);
        float bias = B1b[nt * 16 + r16];
#pragma unroll
        for (int reg = 0; reg < 4; ++reg) {
            int row = quad * 4 + reg;
            bool valid = (node0 + row) < N;
            Sh[wv][row * 72 + nt * 16 + r16] = valid ? (f16)(c[reg] + bias) : (f16)0;
        }
    }
    __syncthreads();
    for (int i = lane; i < 1024; i += 64) {
        int row = i >> 6, col = i & 63;
        int node = node0 + row;
        if (node < N) h1p[(size_t)node * 64 + col] = Sh[wv][row * 72 + col];
    }
    float s = 0.f, s2 = 0.f;
#pragma unroll
    for (int row = 0; row < 16; ++row) {
        float v = (float)Sh[wv][row * 72 + lane];
        s += v;
        s2 = fmaf(v, v, s2);
    }
    red[0][wv][lane] = s;
    red[1][wv][lane] = s2;
    __syncthreads();
    if (wv == 0) {
        float ts  = (red[0][0][lane] + red[0][1][lane]) + (red[0][2][lane] + red[0][3][lane]);
        float ts2 = (red[1][0][lane] + red[1][1][lane]) + (red[1][2][lane] + red[1][3][lane]);
        float* st = statsR + (size_t)(blockIdx.x & (NSTAT - 1)) * 128;
        unsafeAtomicAdd(&st[lane], ts);
        unsafeAtomicAdd(&st[64 + lane], ts2);
    }
}

__global__ void bn_finalize_kernel(const float* __restrict__ statsR,
                                   const float* __restrict__ gamma,
                                   const float* __restrict__ beta,
                                   float* __restrict__ scale, float* __restrict__ shiftv, float n) {
    int f = threadIdx.x;
    if (f >= H) return;
    float s = 0.f, s2 = 0.f;
    for (int r = 0; r < NSTAT; ++r) {
        s  += statsR[r * 128 + f];
        s2 += statsR[r * 128 + 64 + f];
    }
    float mean = s / n;
    float var = s2 / n - mean * mean;   // biased, matches jnp.var
    var = fmaxf(var, 0.f);
    float sc = gamma[f] * rsqrtf(var + 1e-5f);
    scale[f] = sc;
    shiftv[f] = beta[f] - mean * sc;
}

// ---------------------------------------------------------------------------
// MFMA MLP layer 2 + folded head (R13-proven).
// ---------------------------------------------------------------------------
__global__ __launch_bounds__(256)
void mlp2_kernel(const f16* __restrict__ bufC,
                 const f16* __restrict__ pk2a, const f16* __restrict__ pkf,
                 const float* __restrict__ B2a, const float* __restrict__ bf,
                 float* __restrict__ out, int N) {
    __shared__ f16 Su[4][16 * 72];
    int t = threadIdx.x, wv = t >> 6, lane = t & 63;
    int quad = lane >> 4, r16 = lane & 15;
    int node0 = blockIdx.x * 64 + wv * 16;
    int nodeA = node0 + r16;

    v8h a0 = {}, a1 = {};
    if (nodeA < N) {
        a0 = *(const v8h*)(bufC + (size_t)nodeA * 64 + quad * 8);
        a1 = *(const v8h*)(bufC + (size_t)nodeA * 64 + 32 + quad * 8);
    }
#pragma unroll
    for (int nt = 0; nt < 4; ++nt) {
        v8h b0 = *(const v8h*)(pk2a + (((nt * 2 + 0) * 64 + lane) << 3));
        v8h b1 = *(const v8h*)(pk2a + (((nt * 2 + 1) * 64 + lane) << 3));
        v4f c = {0.f, 0.f, 0.f, 0.f};
        c = __builtin_amdgcn_mfma_f32_16x16x32_f16(a0, b0, c, 0, 0, 0);
        c = __builtin_amdgcn_mfma_f32_16x16x32_f16(a1, b1, c, 0, 0, 0);
        float bias = B2a[nt * 16 + r16];
#pragma unroll
        for (int reg = 0; reg < 4; ++reg)
            Su[wv][(quad * 4 + reg) * 72 + nt * 16 + r16] = (f16)fmaxf(c[reg] + bias, 0.f);
    }
    __syncthreads();
    v8h u0 = *(const v8h*)(&Su[wv][r16 * 72 + quad * 8]);
    v8h u1 = *(const v8h*)(&Su[wv][r16 * 72 + 32 + quad * 8]);
    v8h b0 = *(const v8h*)(pkf + ((0 * 64 + lane) << 3));
    v8h b1 = *(const v8h*)(pkf + ((1 * 64 + lane) << 3));
    v4f c = {0.f, 0.f, 0.f, 0.f};
    c = __builtin_amdgcn_mfma_f32_16x16x32_f16(u0, b0, c, 0, 0, 0);
    c = __builtin_amdgcn_mfma_f32_16x16x32_f16(u1, b1, c, 0, 0, 0);
    if (r16 < 10) {
        float bias = bf[r16];
#pragma unroll
        for (int reg = 0; reg < 4; ++reg) {
            int node = node0 + quad * 4 + reg;
            if (node < N) out[(size_t)node * 10 + r16] = c[reg] + bias;
        }
    }
}

extern "C" void kernel_launch(void* const* d_in, const int* in_sizes, int n_in,
                              void* d_out, int out_size, void* d_ws, size_t ws_size,
                              hipStream_t stream) {
    const float* x    = (const float*)d_in[0];
    const int*   ei   = (const int*)d_in[1];
    const float* w1a  = (const float*)d_in[2];
    const float* b1a  = (const float*)d_in[3];
    const float* w1b  = (const float*)d_in[4];
    const float* b1b  = (const float*)d_in[5];
    const float* bng  = (const float*)d_in[6];
    const float* bnb  = (const float*)d_in[7];
    const float* w2a  = (const float*)d_in[8];
    const float* b2a  = (const float*)d_in[9];
    const float* w2b  = (const float*)d_in[10];
    const float* b2b  = (const float*)d_in[11];
    const float* linw = (const float*)d_in[12];
    const float* linb = (const float*)d_in[13];

    int N = in_sizes[0] / H;       // 100000
    int E = in_sizes[1] / 2;       // 1600000
    int CB = (N + CBS - 1) / CBS;  // 196 coarse buckets

    // ---- workspace layout ----
    size_t NH = (size_t)N * H;
    char*  wsb    = (char*)d_ws;
    f16*   xh     = (f16*)wsb;                           // NH fp16
    f16*   bufA   = (f16*)(wsb + NH * 2);                // NH fp16 (agg1 -> h1p in place)
    f16*   bufC   = (f16*)(wsb + NH * 4);                // NH fp16
    float* stats  = (float*)(wsb + NH * 6);              // 128 (legacy, unused)
    float* scale  = stats + 128;                         // 64
    float* shiftv = stats + 192;                         // 64
    float* bf     = stats + 256;                         // 16
    f16*   pk1a   = (f16*)(bf + 16);                     // 4096 (16B-aligned)
    f16*   pk1b   = pk1a + 4096;
    f16*   pk2a   = pk1b + 4096;
    f16*   pkf    = pk2a + 4096;                         // 1024
    int*   gcursor= (int*)(pkf + 1024);                  // 256*16
    int*   gbb    = gcursor + 256 * 16;                  // CB+1
    int*   rowptr = gbb + 257;                           // N+1
    int*   ebuf   = rowptr + (N + 1);                    // E
    int*   pairs  = ebuf + E;                            // CB*CAP slab
    float* statsR = (float*)pairs;                       // NSTAT*128 floats, aliases
                                                         // pairs (dead after bucket_csr)

    int ntiles = (E + TILE - 1) / TILE;

    cvt_init_kernel<<<(int)((NH / 4 + 255) / 256), 256, 0, stream>>>(
        x, xh, (int)(NH / 4), gcursor, CB);
    part_staged_kernel<<<ntiles, 256, 0, stream>>>(ei, gcursor, pairs, E, N, CB);
    scan_cb_kernel<<<1, 256, 0, stream>>>(gcursor, gbb, rowptr, CB, N);
    bucket_csr_kernel<<<CB, 256, 0, stream>>>(pairs, gcursor, gbb, ebuf, rowptr, N);
    repack_kernel<<<(13322 + 255) / 256, 256, 0, stream>>>(
        w1a, w1b, w2a, w2b, b2b, linw, linb, pk1a, pk1b, pk2a, pkf, bf, statsR);

    // 8 nodes per wave -> ceil(N/8) waves -> x64 threads
    int nwaves = (N + 7) / 8;
    int gblocks = (int)(((long long)nwaves * 64 + 255) / 256);
    int mblocks = (N + 63) / 64;
    gather1_kernel<<<gblocks, 256, 0, stream>>>(xh, rowptr, ebuf, bufA, N, E - 1);
    mlp1_kernel<<<mblocks, 256, 0, stream>>>(bufA, bufA, pk1a, pk1b, b1a, b1b, statsR, N);
    bn_finalize_kernel<<<1, 64, 0, stream>>>(statsR, bng, bnb, scale, shiftv, (float)N);

    gather2_kernel<<<gblocks, 256, 0, stream>>>(bufA, scale, shiftv, rowptr, ebuf, bufC, N, E - 1);
    mlp2_kernel<<<mblocks, 256, 0, stream>>>(bufC, pk2a, pkf, b2a, bf, (float*)d_out, N);
}

// Round 3
// 246.056 us; speedup vs baseline: 1.2207x; 1.0075x over previous
//
#include <hip/hip_runtime.h>
#include <hip/hip_fp16.h>

#define H 64
#define CBS 512           // nodes per coarse bucket
#define CB_BITS 9
#define TILE 8192         // edges per partition tile
#define CAP 9216          // slab capacity per bucket
#define NSTAT 64          // BN-stats replicas (contention spreading)
#define RPK_BLKS 53       // ceil(13322/256) repack blocks

typedef _Float16 f16;
typedef __attribute__((ext_vector_type(8))) _Float16 v8h;
typedef __attribute__((ext_vector_type(4))) float v4f;

// ---------------------------------------------------------------------------
// Tiny init: seed slab cursors + zero replicated BN stats. Must precede the
// front kernel (partition atomics on gcursor run concurrently with cvt now).
// ---------------------------------------------------------------------------
__global__ __launch_bounds__(256)
void init_kernel(int* __restrict__ gcursor, float* __restrict__ statsR, int CB) {
    int t = threadIdx.x;
    if (t < CB) gcursor[t * 16] = t * CAP;
    for (int i = t; i < NSTAT * 128; i += 256) statsR[i] = 0.f;
}

// ---------------------------------------------------------------------------
// FRONT: one grid, three independent block ranges.
//   [0, ntiles)              : LDS-staged multi-split edge partition (1 tile/blk)
//   [ntiles, ntiles+53)      : weight repack + folded head
//   [ntiles+53, ...)         : x -> fp16 conversion (streaming)
// Part blocks first so the edge pipeline starts immediately; cvt/repack
// overlap in its shadow instead of serializing as separate dispatches.
// ---------------------------------------------------------------------------
__global__ __launch_bounds__(256)
void front_kernel(const int* __restrict__ ei, int* __restrict__ gcursor,
                  int* __restrict__ pairs, int E, int N, int CB, int ntiles,
                  const float* __restrict__ x, f16* __restrict__ xh, int total4,
                  const float* __restrict__ W1a, const float* __restrict__ W1b,
                  const float* __restrict__ W2a, const float* __restrict__ W2b,
                  const float* __restrict__ B2b, const float* __restrict__ LW,
                  const float* __restrict__ LB,
                  f16* __restrict__ pk1a, f16* __restrict__ pk1b,
                  f16* __restrict__ pk2a, f16* __restrict__ pkf,
                  float* __restrict__ bf) {
    __shared__ int sd[256];
    __shared__ int excl[256];
    __shared__ int gbase[256];
    __shared__ int lcur[256];
    __shared__ int stage[TILE];
    __shared__ unsigned char bin8[TILE];
    int b = blockIdx.x;
    int t = threadIdx.x;

    if (b < ntiles) {
        // ---- edge partition, tile = b (R11-proven body) ----
        int base = b * TILE;
        int cnt = min(TILE, E - base);
        sd[t] = 0;
        __syncthreads();
        for (int i = t; i < cnt; i += 256) {
            int s = ei[base + i];
            int d = ei[E + base + i];
            if ((unsigned)s < (unsigned)N && (unsigned)d < (unsigned)N)
                atomicAdd(&sd[d >> CB_BITS], 1);
        }
        __syncthreads();
        int v = sd[t];
        __syncthreads();
        for (int off = 1; off < 256; off <<= 1) {
            int add = (t >= off) ? sd[t - off] : 0;
            __syncthreads();
            sd[t] += add;
            __syncthreads();
        }
        int ex = sd[t] - v;
        excl[t] = ex;
        lcur[t] = ex;
        if (t < CB && v > 0) gbase[t] = atomicAdd(&gcursor[t * 16], v);
        int tot = sd[255];
        __syncthreads();
        for (int i = t; i < cnt; i += 256) {
            int s = ei[base + i];
            int d = ei[E + base + i];
            if ((unsigned)s < (unsigned)N && (unsigned)d < (unsigned)N) {
                int cb = d >> CB_BITS;
                int pos = atomicAdd(&lcur[cb], 1);
                stage[pos] = s | ((d & (CBS - 1)) << 17);
                bin8[pos] = (unsigned char)cb;
            }
        }
        __syncthreads();
        for (int i = t; i < tot; i += 256) {
            int b8 = bin8[i];
            pairs[gbase[b8] + (i - excl[b8])] = stage[i];
        }
        return;
    }
    b -= ntiles;
    if (b < RPK_BLKS) {
        // ---- weight repack + folded head ----
        int tt = b * 256 + t;
        if (tt < 12288) {
            int m = tt >> 12;
            int e = tt & 4095;
            int j = e & 7, lane = (e >> 3) & 63, ks = (e >> 9) & 1, nt = e >> 10;
            int row = ks * 32 + ((lane >> 4) & 3) * 8 + j;
            int col = nt * 16 + (lane & 15);
            const float* W = (m == 0) ? W1a : (m == 1) ? W1b : W2a;
            f16* P = (m == 0) ? pk1a : (m == 1) ? pk1b : pk2a;
            P[e] = (f16)W[row * 64 + col];
        } else if (tt < 13312) {
            int e = tt - 12288;
            int j = e & 7, lane = (e >> 3) & 63, ks = e >> 9;
            int row = ks * 32 + ((lane >> 4) & 3) * 8 + j;
            int col = lane & 15;
            float a = 0.f;
            if (col < 10)
                for (int m = 0; m < H; ++m) a = fmaf(W2b[row * 64 + m], LW[m * 10 + col], a);
            pkf[e] = (f16)a;
        } else if (tt < 13322) {
            int c = tt - 13312;
            float a = LB[c];
            for (int m = 0; m < H; ++m) a = fmaf(B2b[m], LW[m * 10 + c], a);
            bf[c] = a;
        }
        return;
    }
    b -= RPK_BLKS;
    // ---- x -> fp16 cvt ----
    int i = b * 256 + t;
    if (i >= total4) return;
    float4 v = ((const float4*)x)[i];
    f16 h0 = (f16)v.x, h1 = (f16)v.y, h2 = (f16)v.z, h3 = (f16)v.w;
    ushort4 pk;
    pk.x = *(unsigned short*)&h0; pk.y = *(unsigned short*)&h1;
    pk.z = *(unsigned short*)&h2; pk.w = *(unsigned short*)&h3;
    ((ushort4*)xh)[i] = pk;
}

// ---------------------------------------------------------------------------
// bucket CSR with INLINE bucket-prefix (scan_cb folded in: each block
// recomputes the 196-entry prefix in LDS — cheaper than a dispatch boundary).
// ---------------------------------------------------------------------------
__global__ __launch_bounds__(256)
void bucket_csr_kernel(const int* __restrict__ pairs, const int* __restrict__ gcursor,
                       int* __restrict__ ebuf, int* __restrict__ rowptr, int N, int CB) {
    __shared__ int hist[CBS];
    __shared__ int cur[CBS];
    __shared__ int sd[256];
    __shared__ int carry_s;
    int b = blockIdx.x;
    int t = threadIdx.x;
    // inline prefix over bucket counts
    int c_t = (t < CB) ? (gcursor[t * 16] - t * CAP) : 0;
    sd[t] = c_t; __syncthreads();
    for (int off = 1; off < 256; off <<= 1) {
        int add = (t >= off) ? sd[t - off] : 0;
        __syncthreads();
        sd[t] += add;
        __syncthreads();
    }
    int cnt = gcursor[b * 16] - b * CAP;
    int gb = sd[b] - cnt;                 // exclusive prefix for this bucket
    if (b == 0 && t == 0) rowptr[N] = sd[255];
    __syncthreads();                      // protect sd before reuse below

    int pb = b * CAP;
    for (int i = t; i < CBS; i += 256) hist[i] = 0;
    if (t == 0) carry_s = 0;
    __syncthreads();
    for (int i = t; i < cnt; i += 256)
        atomicAdd(&hist[(pairs[pb + i] >> 17) & (CBS - 1)], 1);
    __syncthreads();
    for (int start = 0; start < CBS; start += 256) {
        int v = hist[start + t];
        sd[t] = v; __syncthreads();
        for (int off = 1; off < 256; off <<= 1) {
            int add = (t >= off) ? sd[t - off] : 0;
            __syncthreads();
            sd[t] += add;
            __syncthreads();
        }
        int ex = sd[t] - v + carry_s;
        cur[start + t] = ex;
        int node = b * CBS + start + t;
        if (node < N) rowptr[node] = gb + ex;
        __syncthreads();
        if (t == 0) carry_s += sd[255];
        __syncthreads();
    }
    for (int i = t; i < cnt; i += 256) {
        int p = pairs[pb + i];
        int pos = atomicAdd(&cur[(p >> 17) & (CBS - 1)], 1);
        ebuf[gb + pos] = p & 0x1FFFF;
    }
}

// ---------------------------------------------------------------------------
// FUSED gather1 + MLP1 + BN stats. Per block: gather 64 nodes (8-row/wave
// 16B/lane loop, 2 rounds/wave) into LDS agg[64][72], then the proven MFMA
// MLP reads A-frags from LDS. Eliminates the bufA round-trip + one launch.
// ---------------------------------------------------------------------------
__global__ __launch_bounds__(256)
void g1mlp1_kernel(const f16* __restrict__ xh, const int* __restrict__ rowptr,
                   const int* __restrict__ ebuf, f16* __restrict__ h1p,
                   const f16* __restrict__ pk1a, const f16* __restrict__ pk1b,
                   const float* __restrict__ B1a, const float* __restrict__ B1b,
                   float* __restrict__ statsR, int N, int Em1) {
    __shared__ f16 agg[64][72];
    __shared__ f16 Su[4][16 * 72];
    __shared__ f16 Sh[4][16 * 72];
    __shared__ float red[2][4][64];
    int t = threadIdx.x, wv = t >> 6, lane = t & 63;
    int g = lane >> 3, fl = lane & 7;
    int node0 = blockIdx.x * 64;

    // ---- gather phase: wave wv covers local rows wv*16 .. wv*16+15 ----
#pragma unroll
    for (int r = 0; r < 2; ++r) {
        int nl = wv * 16 + r * 8 + g;
        int node = node0 + nl;
        bool vn = node < N;
        int p0 = 0, deg = 0;
        if (vn) {
            p0 = rowptr[node];
            deg = rowptr[node + 1] - p0;
        }
        int m = deg;
        m = max(m, __shfl_xor(m, 8));
        m = max(m, __shfl_xor(m, 16));
        m = max(m, __shfl_xor(m, 32));
        float a[8];
        {
            v8h s = {};
            if (vn) s = *(const v8h*)(xh + ((size_t)node << 6) + fl * 8);
#pragma unroll
            for (int j = 0; j < 8; ++j) a[j] = (float)s[j];
        }
        for (int k = 0; k < m; k += 4) {
            int idx[4];
#pragma unroll
            for (int q = 0; q < 4; ++q)
                idx[q] = ebuf[min(p0 + k + q, Em1)];
#pragma unroll
            for (int q = 0; q < 4; ++q) {
                if (k + q < deg) {
                    v8h v = *(const v8h*)(xh + ((size_t)idx[q] << 6) + fl * 8);
#pragma unroll
                    for (int j = 0; j < 8; ++j) a[j] += (float)v[j];
                }
            }
        }
        v8h o;
#pragma unroll
        for (int j = 0; j < 8; ++j) o[j] = (f16)a[j];
        *(v8h*)(&agg[nl][fl * 8]) = o;   // invalid nodes write zeros
    }
    __syncthreads();

    // ---- MFMA MLP phase (proven body; A-frags from LDS) ----
    int quad = lane >> 4, r16 = lane & 15;
    int nodeA_l = wv * 16 + r16;
    v8h a0 = *(const v8h*)(&agg[nodeA_l][quad * 8]);
    v8h a1 = *(const v8h*)(&agg[nodeA_l][32 + quad * 8]);
#pragma unroll
    for (int nt = 0; nt < 4; ++nt) {
        v8h b0 = *(const v8h*)(pk1a + (((nt * 2 + 0) * 64 + lane) << 3));
        v8h b1 = *(const v8h*)(pk1a + (((nt * 2 + 1) * 64 + lane) << 3));
        v4f c = {0.f, 0.f, 0.f, 0.f};
        c = __builtin_amdgcn_mfma_f32_16x16x32_f16(a0, b0, c, 0, 0, 0);
        c = __builtin_amdgcn_mfma_f32_16x16x32_f16(a1, b1, c, 0, 0, 0);
        float bias = B1a[nt * 16 + r16];
#pragma unroll
        for (int reg = 0; reg < 4; ++reg)
            Su[wv][(quad * 4 + reg) * 72 + nt * 16 + r16] = (f16)fmaxf(c[reg] + bias, 0.f);
    }
    __syncthreads();
    v8h u0 = *(const v8h*)(&Su[wv][r16 * 72 + quad * 8]);
    v8h u1 = *(const v8h*)(&Su[wv][r16 * 72 + 32 + quad * 8]);
#pragma unroll
    for (int nt = 0; nt < 4; ++nt) {
        v8h b0 = *(const v8h*)(pk1b + (((nt * 2 + 0) * 64 + lane) << 3));
        v8h b1 = *(const v8h*)(pk1b + (((nt * 2 + 1) * 64 + lane) << 3));
        v4f c = {0.f, 0.f, 0.f, 0.f};
        c = __builtin_amdgcn_mfma_f32_16x16x32_f16(u0, b0, c, 0, 0, 0);
        c = __builtin_amdgcn_mfma_f32_16x16x32_f16(u1, b1, c, 0, 0, 0);
        float bias = B1b[nt * 16 + r16];
#pragma unroll
        for (int reg = 0; reg < 4; ++reg) {
            int row = quad * 4 + reg;
            bool valid = (node0 + wv * 16 + row) < N;
            Sh[wv][row * 72 + nt * 16 + r16] = valid ? (f16)(c[reg] + bias) : (f16)0;
        }
    }
    __syncthreads();
    int nbase = node0 + wv * 16;
    for (int i = lane; i < 1024; i += 64) {
        int row = i >> 6, col = i & 63;
        int node = nbase + row;
        if (node < N) h1p[(size_t)node * 64 + col] = Sh[wv][row * 72 + col];
    }
    float s = 0.f, s2 = 0.f;
#pragma unroll
    for (int row = 0; row < 16; ++row) {
        float v = (float)Sh[wv][row * 72 + lane];
        s += v;
        s2 = fmaf(v, v, s2);
    }
    red[0][wv][lane] = s;
    red[1][wv][lane] = s2;
    __syncthreads();
    if (wv == 0) {
        float ts  = (red[0][0][lane] + red[0][1][lane]) + (red[0][2][lane] + red[0][3][lane]);
        float ts2 = (red[1][0][lane] + red[1][1][lane]) + (red[1][2][lane] + red[1][3][lane]);
        float* st = statsR + (size_t)(blockIdx.x & (NSTAT - 1)) * 128;
        unsafeAtomicAdd(&st[lane], ts);
        unsafeAtomicAdd(&st[64 + lane], ts2);
    }
}

__global__ void bn_finalize_kernel(const float* __restrict__ statsR,
                                   const float* __restrict__ gamma,
                                   const float* __restrict__ beta,
                                   float* __restrict__ scale, float* __restrict__ shiftv, float n) {
    int f = threadIdx.x;
    if (f >= H) return;
    float s = 0.f, s2 = 0.f;
    for (int r = 0; r < NSTAT; ++r) {
        s  += statsR[r * 128 + f];
        s2 += statsR[r * 128 + 64 + f];
    }
    float mean = s / n;
    float var = s2 / n - mean * mean;   // biased, matches jnp.var
    var = fmaxf(var, 0.f);
    float sc = gamma[f] * rsqrtf(var + 1e-5f);
    scale[f] = sc;
    shiftv[f] = beta[f] - mean * sc;
}

// ---------------------------------------------------------------------------
// FUSED gather2 (+BN fold) + MLP2 + folded head. Eliminates bufC.
// ---------------------------------------------------------------------------
__global__ __launch_bounds__(256)
void g2mlp2_kernel(const f16* __restrict__ h1p, const float* __restrict__ scale,
                   const float* __restrict__ shiftv, const int* __restrict__ rowptr,
                   const int* __restrict__ ebuf,
                   const f16* __restrict__ pk2a, const f16* __restrict__ pkf,
                   const float* __restrict__ B2a, const float* __restrict__ bf,
                   float* __restrict__ out, int N, int Em1) {
    __shared__ f16 agg[64][72];
    __shared__ f16 Su[4][16 * 72];
    int t = threadIdx.x, wv = t >> 6, lane = t & 63;
    int g = lane >> 3, fl = lane & 7;
    int node0 = blockIdx.x * 64;

    float sc[8], sh[8];
    {
        float4 s0 = *(const float4*)(scale + fl * 8);
        float4 s1 = *(const float4*)(scale + fl * 8 + 4);
        float4 h0 = *(const float4*)(shiftv + fl * 8);
        float4 h1 = *(const float4*)(shiftv + fl * 8 + 4);
        sc[0]=s0.x; sc[1]=s0.y; sc[2]=s0.z; sc[3]=s0.w;
        sc[4]=s1.x; sc[5]=s1.y; sc[6]=s1.z; sc[7]=s1.w;
        sh[0]=h0.x; sh[1]=h0.y; sh[2]=h0.z; sh[3]=h0.w;
        sh[4]=h1.x; sh[5]=h1.y; sh[6]=h1.z; sh[7]=h1.w;
    }

#pragma unroll
    for (int r = 0; r < 2; ++r) {
        int nl = wv * 16 + r * 8 + g;
        int node = node0 + nl;
        bool vn = node < N;
        int p0 = 0, deg = 0;
        if (vn) {
            p0 = rowptr[node];
            deg = rowptr[node + 1] - p0;
        }
        int m = deg;
        m = max(m, __shfl_xor(m, 8));
        m = max(m, __shfl_xor(m, 16));
        m = max(m, __shfl_xor(m, 32));
        float a[8];
        {
            v8h s = {};
            if (vn) s = *(const v8h*)(h1p + ((size_t)node << 6) + fl * 8);
#pragma unroll
            for (int j = 0; j < 8; ++j) a[j] = (float)s[j];
        }
        for (int k = 0; k < m; k += 4) {
            int idx[4];
#pragma unroll
            for (int q = 0; q < 4; ++q)
                idx[q] = ebuf[min(p0 + k + q, Em1)];
#pragma unroll
            for (int q = 0; q < 4; ++q) {
                if (k + q < deg) {
                    v8h v = *(const v8h*)(h1p + ((size_t)idx[q] << 6) + fl * 8);
#pragma unroll
                    for (int j = 0; j < 8; ++j) a[j] += (float)v[j];
                }
            }
        }
        float degp1 = (float)(deg + 1);
        v8h o;
#pragma unroll
        for (int j = 0; j < 8; ++j) o[j] = (f16)(a[j] * sc[j] + degp1 * sh[j]);
        *(v8h*)(&agg[nl][fl * 8]) = o;
    }
    __syncthreads();

    int quad = lane >> 4, r16 = lane & 15;
    int nodeA_l = wv * 16 + r16;
    v8h a0 = *(const v8h*)(&agg[nodeA_l][quad * 8]);
    v8h a1 = *(const v8h*)(&agg[nodeA_l][32 + quad * 8]);
#pragma unroll
    for (int nt = 0; nt < 4; ++nt) {
        v8h b0 = *(const v8h*)(pk2a + (((nt * 2 + 0) * 64 + lane) << 3));
        v8h b1 = *(const v8h*)(pk2a + (((nt * 2 + 1) * 64 + lane) << 3));
        v4f c = {0.f, 0.f, 0.f, 0.f};
        c = __builtin_amdgcn_mfma_f32_16x16x32_f16(a0, b0, c, 0, 0, 0);
        c = __builtin_amdgcn_mfma_f32_16x16x32_f16(a1, b1, c, 0, 0, 0);
        float bias = B2a[nt * 16 + r16];
#pragma unroll
        for (int reg = 0; reg < 4; ++reg)
            Su[wv][(quad * 4 + reg) * 72 + nt * 16 + r16] = (f16)fmaxf(c[reg] + bias, 0.f);
    }
    __syncthreads();
    v8h u0 = *(const v8h*)(&Su[wv][r16 * 72 + quad * 8]);
    v8h u1 = *(const v8h*)(&Su[wv][r16 * 72 + 32 + quad * 8]);
    v8h b0 = *(const v8h*)(pkf + ((0 * 64 + lane) << 3));
    v8h b1 = *(const v8h*)(pkf + ((1 * 64 + lane) << 3));
    v4f c = {0.f, 0.f, 0.f, 0.f};
    c = __builtin_amdgcn_mfma_f32_16x16x32_f16(u0, b0, c, 0, 0, 0);
    c = __builtin_amdgcn_mfma_f32_16x16x32_f16(u1, b1, c, 0, 0, 0);
    if (r16 < 10) {
        float bias = bf[r16];
#pragma unroll
        for (int reg = 0; reg < 4; ++reg) {
            int node = node0 + wv * 16 + quad * 4 + reg;
            if (node < N) out[(size_t)node * 10 + r16] = c[reg] + bias;
        }
    }
}

extern "C" void kernel_launch(void* const* d_in, const int* in_sizes, int n_in,
                              void* d_out, int out_size, void* d_ws, size_t ws_size,
                              hipStream_t stream) {
    const float* x    = (const float*)d_in[0];
    const int*   ei   = (const int*)d_in[1];
    const float* w1a  = (const float*)d_in[2];
    const float* b1a  = (const float*)d_in[3];
    const float* w1b  = (const float*)d_in[4];
    const float* b1b  = (const float*)d_in[5];
    const float* bng  = (const float*)d_in[6];
    const float* bnb  = (const float*)d_in[7];
    const float* w2a  = (const float*)d_in[8];
    const float* b2a  = (const float*)d_in[9];
    const float* w2b  = (const float*)d_in[10];
    const float* b2b  = (const float*)d_in[11];
    const float* linw = (const float*)d_in[12];
    const float* linb = (const float*)d_in[13];

    int N = in_sizes[0] / H;       // 100000
    int E = in_sizes[1] / 2;       // 1600000
    int CB = (N + CBS - 1) / CBS;  // 196 coarse buckets

    // ---- workspace layout ----
    size_t NH = (size_t)N * H;
    char*  wsb    = (char*)d_ws;
    f16*   xh     = (f16*)wsb;                           // NH fp16
    f16*   h1p    = (f16*)(wsb + NH * 2);                // NH fp16 (mlp1 out)
    float* stats  = (float*)(wsb + NH * 6);              // 128 (legacy, unused)
    float* scale  = stats + 128;                         // 64
    float* shiftv = stats + 192;                         // 64
    float* bf     = stats + 256;                         // 16
    f16*   pk1a   = (f16*)(bf + 16);                     // 4096 (16B-aligned)
    f16*   pk1b   = pk1a + 4096;
    f16*   pk2a   = pk1b + 4096;
    f16*   pkf    = pk2a + 4096;                         // 1024
    int*   gcursor= (int*)(pkf + 1024);                  // 256*16
    int*   rowptr = gcursor + 256 * 16;                  // N+1
    int*   ebuf   = rowptr + (N + 1);                    // E
    int*   pairs  = ebuf + E;                            // CB*CAP slab
    float* statsR = (float*)(pairs + (size_t)CB * CAP);  // NSTAT*128 (own slot now:
                                                         // repack runs ∥ partition)

    int ntiles = (E + TILE - 1) / TILE;
    int total4 = (int)(NH / 4);
    int cvtblocks = (total4 + 255) / 256;
    int mblocks = (N + 63) / 64;

    init_kernel<<<1, 256, 0, stream>>>(gcursor, statsR, CB);
    front_kernel<<<ntiles + RPK_BLKS + cvtblocks, 256, 0, stream>>>(
        ei, gcursor, pairs, E, N, CB, ntiles,
        x, xh, total4,
        w1a, w1b, w2a, w2b, b2b, linw, linb,
        pk1a, pk1b, pk2a, pkf, bf);
    bucket_csr_kernel<<<CB, 256, 0, stream>>>(pairs, gcursor, ebuf, rowptr, N, CB);
    g1mlp1_kernel<<<mblocks, 256, 0, stream>>>(
        xh, rowptr, ebuf, h1p, pk1a, pk1b, b1a, b1b, statsR, N, E - 1);
    bn_finalize_kernel<<<1, 64, 0, stream>>>(statsR, bng, bnb, scale, shiftv, (float)N);
    g2mlp2_kernel<<<mblocks, 256, 0, stream>>>(
        h1p, scale, shiftv, rowptr, ebuf, pk2a, pkf, b2a, bf, (float*)d_out, N, E - 1);
}

// Round 4
// 232.435 us; speedup vs baseline: 1.2922x; 1.0586x over previous
//
#include <hip/hip_runtime.h>
#include <hip/hip_fp16.h>

#define H 64
#define CBS 512           // nodes per coarse bucket
#define CB_BITS 9
#define TILE 8192         // edges per partition tile
#define CAP 9216          // slab capacity per bucket
#define NSTAT 64          // BN-stats replicas (contention spreading)
#define RPK_BLKS 53       // ceil(13322/256) repack blocks

typedef _Float16 f16;
typedef __attribute__((ext_vector_type(8))) _Float16 v8h;
typedef __attribute__((ext_vector_type(4))) float v4f;

// ---------------------------------------------------------------------------
// Tiny init: seed slab cursors + zero replicated BN stats.
// ---------------------------------------------------------------------------
__global__ __launch_bounds__(256)
void init_kernel(int* __restrict__ gcursor, float* __restrict__ statsR, int CB) {
    int t = threadIdx.x;
    if (t < CB) gcursor[t * 16] = t * CAP;
    for (int i = t; i < NSTAT * 128; i += 256) statsR[i] = 0.f;
}

// ---------------------------------------------------------------------------
// FRONT: one grid, three independent block ranges (R3-proven).
//   [0, ntiles)         : LDS-staged multi-split edge partition
//   [ntiles, +53)       : weight repack + folded head
//   [ntiles+53, ...)    : x -> fp16 conversion (streaming)
// ---------------------------------------------------------------------------
__global__ __launch_bounds__(256)
void front_kernel(const int* __restrict__ ei, int* __restrict__ gcursor,
                  int* __restrict__ pairs, int E, int N, int CB, int ntiles,
                  const float* __restrict__ x, f16* __restrict__ xh, int total4,
                  const float* __restrict__ W1a, const float* __restrict__ W1b,
                  const float* __restrict__ W2a, const float* __restrict__ W2b,
                  const float* __restrict__ B2b, const float* __restrict__ LW,
                  const float* __restrict__ LB,
                  f16* __restrict__ pk1a, f16* __restrict__ pk1b,
                  f16* __restrict__ pk2a, f16* __restrict__ pkf,
                  float* __restrict__ bf) {
    __shared__ int sd[256];
    __shared__ int excl[256];
    __shared__ int gbase[256];
    __shared__ int lcur[256];
    __shared__ int stage[TILE];
    __shared__ unsigned char bin8[TILE];
    int b = blockIdx.x;
    int t = threadIdx.x;

    if (b < ntiles) {
        int base = b * TILE;
        int cnt = min(TILE, E - base);
        sd[t] = 0;
        __syncthreads();
        for (int i = t; i < cnt; i += 256) {
            int s = ei[base + i];
            int d = ei[E + base + i];
            if ((unsigned)s < (unsigned)N && (unsigned)d < (unsigned)N)
                atomicAdd(&sd[d >> CB_BITS], 1);
        }
        __syncthreads();
        int v = sd[t];
        __syncthreads();
        for (int off = 1; off < 256; off <<= 1) {
            int add = (t >= off) ? sd[t - off] : 0;
            __syncthreads();
            sd[t] += add;
            __syncthreads();
        }
        int ex = sd[t] - v;
        excl[t] = ex;
        lcur[t] = ex;
        if (t < CB && v > 0) gbase[t] = atomicAdd(&gcursor[t * 16], v);
        int tot = sd[255];
        __syncthreads();
        for (int i = t; i < cnt; i += 256) {
            int s = ei[base + i];
            int d = ei[E + base + i];
            if ((unsigned)s < (unsigned)N && (unsigned)d < (unsigned)N) {
                int cb = d >> CB_BITS;
                int pos = atomicAdd(&lcur[cb], 1);
                stage[pos] = s | ((d & (CBS - 1)) << 17);
                bin8[pos] = (unsigned char)cb;
            }
        }
        __syncthreads();
        for (int i = t; i < tot; i += 256) {
            int b8 = bin8[i];
            pairs[gbase[b8] + (i - excl[b8])] = stage[i];
        }
        return;
    }
    b -= ntiles;
    if (b < RPK_BLKS) {
        int tt = b * 256 + t;
        if (tt < 12288) {
            int m = tt >> 12;
            int e = tt & 4095;
            int j = e & 7, lane = (e >> 3) & 63, ks = (e >> 9) & 1, nt = e >> 10;
            int row = ks * 32 + ((lane >> 4) & 3) * 8 + j;
            int col = nt * 16 + (lane & 15);
            const float* W = (m == 0) ? W1a : (m == 1) ? W1b : W2a;
            f16* P = (m == 0) ? pk1a : (m == 1) ? pk1b : pk2a;
            P[e] = (f16)W[row * 64 + col];
        } else if (tt < 13312) {
            int e = tt - 12288;
            int j = e & 7, lane = (e >> 3) & 63, ks = e >> 9;
            int row = ks * 32 + ((lane >> 4) & 3) * 8 + j;
            int col = lane & 15;
            float a = 0.f;
            if (col < 10)
                for (int m = 0; m < H; ++m) a = fmaf(W2b[row * 64 + m], LW[m * 10 + col], a);
            pkf[e] = (f16)a;
        } else if (tt < 13322) {
            int c = tt - 13312;
            float a = LB[c];
            for (int m = 0; m < H; ++m) a = fmaf(B2b[m], LW[m * 10 + c], a);
            bf[c] = a;
        }
        return;
    }
    b -= RPK_BLKS;
    int i = b * 256 + t;
    if (i >= total4) return;
    float4 v = ((const float4*)x)[i];
    f16 h0 = (f16)v.x, h1 = (f16)v.y, h2 = (f16)v.z, h3 = (f16)v.w;
    ushort4 pk;
    pk.x = *(unsigned short*)&h0; pk.y = *(unsigned short*)&h1;
    pk.z = *(unsigned short*)&h2; pk.w = *(unsigned short*)&h3;
    ((ushort4*)xh)[i] = pk;
}

// ---------------------------------------------------------------------------
// bucket CSR with inline bucket-prefix (R3-proven).
// ---------------------------------------------------------------------------
__global__ __launch_bounds__(256)
void bucket_csr_kernel(const int* __restrict__ pairs, const int* __restrict__ gcursor,
                       int* __restrict__ ebuf, int* __restrict__ rowptr, int N, int CB) {
    __shared__ int hist[CBS];
    __shared__ int cur[CBS];
    __shared__ int sd[256];
    __shared__ int carry_s;
    int b = blockIdx.x;
    int t = threadIdx.x;
    int c_t = (t < CB) ? (gcursor[t * 16] - t * CAP) : 0;
    sd[t] = c_t; __syncthreads();
    for (int off = 1; off < 256; off <<= 1) {
        int add = (t >= off) ? sd[t - off] : 0;
        __syncthreads();
        sd[t] += add;
        __syncthreads();
    }
    int cnt = gcursor[b * 16] - b * CAP;
    int gb = sd[b] - cnt;
    if (b == 0 && t == 0) rowptr[N] = sd[255];
    __syncthreads();

    int pb = b * CAP;
    for (int i = t; i < CBS; i += 256) hist[i] = 0;
    if (t == 0) carry_s = 0;
    __syncthreads();
    for (int i = t; i < cnt; i += 256)
        atomicAdd(&hist[(pairs[pb + i] >> 17) & (CBS - 1)], 1);
    __syncthreads();
    for (int start = 0; start < CBS; start += 256) {
        int v = hist[start + t];
        sd[t] = v; __syncthreads();
        for (int off = 1; off < 256; off <<= 1) {
            int add = (t >= off) ? sd[t - off] : 0;
            __syncthreads();
            sd[t] += add;
            __syncthreads();
        }
        int ex = sd[t] - v + carry_s;
        cur[start + t] = ex;
        int node = b * CBS + start + t;
        if (node < N) rowptr[node] = gb + ex;
        __syncthreads();
        if (t == 0) carry_s += sd[255];
        __syncthreads();
    }
    for (int i = t; i < cnt; i += 256) {
        int p = pairs[pb + i];
        int pos = atomicAdd(&cur[(p >> 17) & (CBS - 1)], 1);
        ebuf[gb + pos] = p & 0x1FFFF;
    }
}

// ---------------------------------------------------------------------------
// Layer-1 gather, split + 8-wide branch-free fast path: 8 nodes/wave,
// 8 lanes/row, 16B/lane. Per-group divergent loop (no wave-max waste);
// full chunks issue 8 idx + 8 row-gathers with no predication branches.
// ---------------------------------------------------------------------------
__global__ __launch_bounds__(256)
void gather1_kernel(const f16* __restrict__ xh, const int* __restrict__ rowptr,
                    const int* __restrict__ ebuf, f16* __restrict__ bufA,
                    int N, int Em1) {
    int wid = (int)(((long long)blockIdx.x * blockDim.x + threadIdx.x) >> 6);
    int lane = threadIdx.x & 63;
    int g = lane >> 3, fl = lane & 7;
    int node = wid * 8 + g;
    bool vn = node < N;
    int p0 = 0, deg = 0;
    if (vn) {
        p0 = rowptr[node];
        deg = rowptr[node + 1] - p0;
    }
    float a[8];
    {
        v8h s = {};
        if (vn) s = *(const v8h*)(xh + ((size_t)node << 6) + fl * 8);
#pragma unroll
        for (int j = 0; j < 8; ++j) a[j] = (float)s[j];
    }
    int k = 0;
    for (; k + 8 <= deg; k += 8) {
        int idx[8];
#pragma unroll
        for (int q = 0; q < 8; ++q) idx[q] = ebuf[p0 + k + q];
#pragma unroll
        for (int q = 0; q < 8; ++q) {
            v8h v = *(const v8h*)(xh + ((size_t)idx[q] << 6) + fl * 8);
#pragma unroll
            for (int j = 0; j < 8; ++j) a[j] += (float)v[j];
        }
    }
    if (k < deg) {
        int idx[8];
#pragma unroll
        for (int q = 0; q < 8; ++q) idx[q] = ebuf[min(p0 + k + q, Em1)];
#pragma unroll
        for (int q = 0; q < 8; ++q) {
            if (k + q < deg) {
                v8h v = *(const v8h*)(xh + ((size_t)idx[q] << 6) + fl * 8);
#pragma unroll
                for (int j = 0; j < 8; ++j) a[j] += (float)v[j];
            }
        }
    }
    if (vn) {
        v8h o;
#pragma unroll
        for (int j = 0; j < 8; ++j) o[j] = (f16)a[j];
        *(v8h*)(bufA + ((size_t)node << 6) + fl * 8) = o;
    }
}

// ---------------------------------------------------------------------------
// Layer-2 gather, same shape, with self term + folded BN.
// ---------------------------------------------------------------------------
__global__ __launch_bounds__(256)
void gather2_kernel(const f16* __restrict__ h1p, const float* __restrict__ scale,
                    const float* __restrict__ shiftv, const int* __restrict__ rowptr,
                    const int* __restrict__ ebuf, f16* __restrict__ bufC,
                    int N, int Em1) {
    int wid = (int)(((long long)blockIdx.x * blockDim.x + threadIdx.x) >> 6);
    int lane = threadIdx.x & 63;
    int g = lane >> 3, fl = lane & 7;
    int node = wid * 8 + g;
    bool vn = node < N;
    int p0 = 0, deg = 0;
    if (vn) {
        p0 = rowptr[node];
        deg = rowptr[node + 1] - p0;
    }
    float a[8];
    {
        v8h s = {};
        if (vn) s = *(const v8h*)(h1p + ((size_t)node << 6) + fl * 8);
#pragma unroll
        for (int j = 0; j < 8; ++j) a[j] = (float)s[j];
    }
    int k = 0;
    for (; k + 8 <= deg; k += 8) {
        int idx[8];
#pragma unroll
        for (int q = 0; q < 8; ++q) idx[q] = ebuf[p0 + k + q];
#pragma unroll
        for (int q = 0; q < 8; ++q) {
            v8h v = *(const v8h*)(h1p + ((size_t)idx[q] << 6) + fl * 8);
#pragma unroll
            for (int j = 0; j < 8; ++j) a[j] += (float)v[j];
        }
    }
    if (k < deg) {
        int idx[8];
#pragma unroll
        for (int q = 0; q < 8; ++q) idx[q] = ebuf[min(p0 + k + q, Em1)];
#pragma unroll
        for (int q = 0; q < 8; ++q) {
            if (k + q < deg) {
                v8h v = *(const v8h*)(h1p + ((size_t)idx[q] << 6) + fl * 8);
#pragma unroll
                for (int j = 0; j < 8; ++j) a[j] += (float)v[j];
            }
        }
    }
    if (vn) {
        float4 s0 = *(const float4*)(scale + fl * 8);
        float4 s1 = *(const float4*)(scale + fl * 8 + 4);
        float4 h0 = *(const float4*)(shiftv + fl * 8);
        float4 h1 = *(const float4*)(shiftv + fl * 8 + 4);
        float degp1 = (float)(deg + 1);
        float sc[8] = {s0.x, s0.y, s0.z, s0.w, s1.x, s1.y, s1.z, s1.w};
        float sh[8] = {h0.x, h0.y, h0.z, h0.w, h1.x, h1.y, h1.z, h1.w};
        v8h o;
#pragma unroll
        for (int j = 0; j < 8; ++j) o[j] = (f16)(a[j] * sc[j] + degp1 * sh[j]);
        *(v8h*)(bufC + ((size_t)node << 6) + fl * 8) = o;
    }
}

// ---------------------------------------------------------------------------
// MFMA MLP layer 1 + fused BN stats into replicated accumulators (R2-proven).
// ---------------------------------------------------------------------------
__global__ __launch_bounds__(256)
void mlp1_kernel(const f16* __restrict__ bufA, f16* __restrict__ h1p,
                 const f16* __restrict__ pk1a, const f16* __restrict__ pk1b,
                 const float* __restrict__ B1a, const float* __restrict__ B1b,
                 float* __restrict__ statsR, int N) {
    __shared__ f16 Su[4][16 * 72];
    __shared__ f16 Sh[4][16 * 72];
    __shared__ float red[2][4][64];
    int t = threadIdx.x, wv = t >> 6, lane = t & 63;
    int quad = lane >> 4, r16 = lane & 15;
    int node0 = blockIdx.x * 64 + wv * 16;
    int nodeA = node0 + r16;

    v8h a0 = {}, a1 = {};
    if (nodeA < N) {
        a0 = *(const v8h*)(bufA + (size_t)nodeA * 64 + quad * 8);
        a1 = *(const v8h*)(bufA + (size_t)nodeA * 64 + 32 + quad * 8);
    }
#pragma unroll
    for (int nt = 0; nt < 4; ++nt) {
        v8h b0 = *(const v8h*)(pk1a + (((nt * 2 + 0) * 64 + lane) << 3));
        v8h b1 = *(const v8h*)(pk1a + (((nt * 2 + 1) * 64 + lane) << 3));
        v4f c = {0.f, 0.f, 0.f, 0.f};
        c = __builtin_amdgcn_mfma_f32_16x16x32_f16(a0, b0, c, 0, 0, 0);
        c = __builtin_amdgcn_mfma_f32_16x16x32_f16(a1, b1, c, 0, 0, 0);
        float bias = B1a[nt * 16 + r16];
#pragma unroll
        for (int reg = 0; reg < 4; ++reg)
            Su[wv][(quad * 4 + reg) * 72 + nt * 16 + r16] = (f16)fmaxf(c[reg] + bias, 0.f);
    }
    __syncthreads();
    v8h u0 = *(const v8h*)(&Su[wv][r16 * 72 + quad * 8]);
    v8h u1 = *(const v8h*)(&Su[wv][r16 * 72 + 32 + quad * 8]);
#pragma unroll
    for (int nt = 0; nt < 4; ++nt) {
        v8h b0 = *(const v8h*)(pk1b + (((nt * 2 + 0) * 64 + lane) << 3));
        v8h b1 = *(const v8h*)(pk1b + (((nt * 2 + 1) * 64 + lane) << 3));
        v4f c = {0.f, 0.f, 0.f, 0.f};
        c = __builtin_amdgcn_mfma_f32_16x16x32_f16(u0, b0, c, 0, 0, 0);
        c = __builtin_amdgcn_mfma_f32_16x16x32_f16(u1, b1, c, 0, 0, 0);
        float bias = B1b[nt * 16 + r16];
#pragma unroll
        for (int reg = 0; reg < 4; ++reg) {
            int row = quad * 4 + reg;
            bool valid = (node0 + row) < N;
            Sh[wv][row * 72 + nt * 16 + r16] = valid ? (f16)(c[reg] + bias) : (f16)0;
        }
    }
    __syncthreads();
    for (int i = lane; i < 1024; i += 64) {
        int row = i >> 6, col = i & 63;
        int node = node0 + row;
        if (node < N) h1p[(size_t)node * 64 + col] = Sh[wv][row * 72 + col];
    }
    float s = 0.f, s2 = 0.f;
#pragma unroll
    for (int row = 0; row < 16; ++row) {
        float v = (float)Sh[wv][row * 72 + lane];
        s += v;
        s2 = fmaf(v, v, s2);
    }
    red[0][wv][lane] = s;
    red[1][wv][lane] = s2;
    __syncthreads();
    if (wv == 0) {
        float ts  = (red[0][0][lane] + red[0][1][lane]) + (red[0][2][lane] + red[0][3][lane]);
        float ts2 = (red[1][0][lane] + red[1][1][lane]) + (red[1][2][lane] + red[1][3][lane]);
        float* st = statsR + (size_t)(blockIdx.x & (NSTAT - 1)) * 128;
        unsafeAtomicAdd(&st[lane], ts);
        unsafeAtomicAdd(&st[64 + lane], ts2);
    }
}

__global__ void bn_finalize_kernel(const float* __restrict__ statsR,
                                   const float* __restrict__ gamma,
                                   const float* __restrict__ beta,
                                   float* __restrict__ scale, float* __restrict__ shiftv, float n) {
    int f = threadIdx.x;
    if (f >= H) return;
    float s = 0.f, s2 = 0.f;
    for (int r = 0; r < NSTAT; ++r) {
        s  += statsR[r * 128 + f];
        s2 += statsR[r * 128 + 64 + f];
    }
    float mean = s / n;
    float var = s2 / n - mean * mean;   // biased, matches jnp.var
    var = fmaxf(var, 0.f);
    float sc = gamma[f] * rsqrtf(var + 1e-5f);
    scale[f] = sc;
    shiftv[f] = beta[f] - mean * sc;
}

// ---------------------------------------------------------------------------
// MFMA MLP layer 2 + folded head (R2-proven).
// ---------------------------------------------------------------------------
__global__ __launch_bounds__(256)
void mlp2_kernel(const f16* __restrict__ bufC,
                 const f16* __restrict__ pk2a, const f16* __restrict__ pkf,
                 const float* __restrict__ B2a, const float* __restrict__ bf,
                 float* __restrict__ out, int N) {
    __shared__ f16 Su[4][16 * 72];
    int t = threadIdx.x, wv = t >> 6, lane = t & 63;
    int quad = lane >> 4, r16 = lane & 15;
    int node0 = blockIdx.x * 64 + wv * 16;
    int nodeA = node0 + r16;

    v8h a0 = {}, a1 = {};
    if (nodeA < N) {
        a0 = *(const v8h*)(bufC + (size_t)nodeA * 64 + quad * 8);
        a1 = *(const v8h*)(bufC + (size_t)nodeA * 64 + 32 + quad * 8);
    }
#pragma unroll
    for (int nt = 0; nt < 4; ++nt) {
        v8h b0 = *(const v8h*)(pk2a + (((nt * 2 + 0) * 64 + lane) << 3));
        v8h b1 = *(const v8h*)(pk2a + (((nt * 2 + 1) * 64 + lane) << 3));
        v4f c = {0.f, 0.f, 0.f, 0.f};
        c = __builtin_amdgcn_mfma_f32_16x16x32_f16(a0, b0, c, 0, 0, 0);
        c = __builtin_amdgcn_mfma_f32_16x16x32_f16(a1, b1, c, 0, 0, 0);
        float bias = B2a[nt * 16 + r16];
#pragma unroll
        for (int reg = 0; reg < 4; ++reg)
            Su[wv][(quad * 4 + reg) * 72 + nt * 16 + r16] = (f16)fmaxf(c[reg] + bias, 0.f);
    }
    __syncthreads();
    v8h u0 = *(const v8h*)(&Su[wv][r16 * 72 + quad * 8]);
    v8h u1 = *(const v8h*)(&Su[wv][r16 * 72 + 32 + quad * 8]);
    v8h b0 = *(const v8h*)(pkf + ((0 * 64 + lane) << 3));
    v8h b1 = *(const v8h*)(pkf + ((1 * 64 + lane) << 3));
    v4f c = {0.f, 0.f, 0.f, 0.f};
    c = __builtin_amdgcn_mfma_f32_16x16x32_f16(u0, b0, c, 0, 0, 0);
    c = __builtin_amdgcn_mfma_f32_16x16x32_f16(u1, b1, c, 0, 0, 0);
    if (r16 < 10) {
        float bias = bf[r16];
#pragma unroll
        for (int reg = 0; reg < 4; ++reg) {
            int node = node0 + quad * 4 + reg;
            if (node < N) out[(size_t)node * 10 + r16] = c[reg] + bias;
        }
    }
}

extern "C" void kernel_launch(void* const* d_in, const int* in_sizes, int n_in,
                              void* d_out, int out_size, void* d_ws, size_t ws_size,
                              hipStream_t stream) {
    const float* x    = (const float*)d_in[0];
    const int*   ei   = (const int*)d_in[1];
    const float* w1a  = (const float*)d_in[2];
    const float* b1a  = (const float*)d_in[3];
    const float* w1b  = (const float*)d_in[4];
    const float* b1b  = (const float*)d_in[5];
    const float* bng  = (const float*)d_in[6];
    const float* bnb  = (const float*)d_in[7];
    const float* w2a  = (const float*)d_in[8];
    const float* b2a  = (const float*)d_in[9];
    const float* w2b  = (const float*)d_in[10];
    const float* b2b  = (const float*)d_in[11];
    const float* linw = (const float*)d_in[12];
    const float* linb = (const float*)d_in[13];

    int N = in_sizes[0] / H;       // 100000
    int E = in_sizes[1] / 2;       // 1600000
    int CB = (N + CBS - 1) / CBS;  // 196 coarse buckets

    // ---- workspace layout ----
    size_t NH = (size_t)N * H;
    char*  wsb    = (char*)d_ws;
    f16*   xh     = (f16*)wsb;                           // NH fp16
    f16*   bufA   = (f16*)(wsb + NH * 2);                // NH fp16 (agg1 -> h1p in place)
    f16*   bufC   = (f16*)(wsb + NH * 4);                // NH fp16
    float* stats  = (float*)(wsb + NH * 6);              // 128 (legacy, unused)
    float* scale  = stats + 128;                         // 64
    float* shiftv = stats + 192;                         // 64
    float* bf     = stats + 256;                         // 16
    f16*   pk1a   = (f16*)(bf + 16);                     // 4096 (16B-aligned)
    f16*   pk1b   = pk1a + 4096;
    f16*   pk2a   = pk1b + 4096;
    f16*   pkf    = pk2a + 4096;                         // 1024
    int*   gcursor= (int*)(pkf + 1024);                  // 256*16
    int*   rowptr = gcursor + 256 * 16;                  // N+1
    int*   ebuf   = rowptr + (N + 1);                    // E
    int*   pairs  = ebuf + E;                            // CB*CAP slab
    float* statsR = (float*)(pairs + (size_t)CB * CAP);  // NSTAT*128 (own slot)

    int ntiles = (E + TILE - 1) / TILE;
    int total4 = (int)(NH / 4);
    int cvtblocks = (total4 + 255) / 256;
    int mblocks = (N + 63) / 64;
    int nwaves = (N + 7) / 8;
    int gblocks = (int)(((long long)nwaves * 64 + 255) / 256);

    init_kernel<<<1, 256, 0, stream>>>(gcursor, statsR, CB);
    front_kernel<<<ntiles + RPK_BLKS + cvtblocks, 256, 0, stream>>>(
        ei, gcursor, pairs, E, N, CB, ntiles,
        x, xh, total4,
        w1a, w1b, w2a, w2b, b2b, linw, linb,
        pk1a, pk1b, pk2a, pkf, bf);
    bucket_csr_kernel<<<CB, 256, 0, stream>>>(pairs, gcursor, ebuf, rowptr, N, CB);

    gather1_kernel<<<gblocks, 256, 0, stream>>>(xh, rowptr, ebuf, bufA, N, E - 1);
    mlp1_kernel<<<mblocks, 256, 0, stream>>>(bufA, bufA, pk1a, pk1b, b1a, b1b, statsR, N);
    bn_finalize_kernel<<<1, 64, 0, stream>>>(statsR, bng, bnb, scale, shiftv, (float)N);

    gather2_kernel<<<gblocks, 256, 0, stream>>>(bufA, scale, shiftv, rowptr, ebuf, bufC, N, E - 1);
    mlp2_kernel<<<mblocks, 256, 0, stream>>>(bufC, pk2a, pkf, b2a, bf, (float*)d_out, N);
}

// Round 5
// 230.728 us; speedup vs baseline: 1.3018x; 1.0074x over previous
//
#include <hip/hip_runtime.h>
#include <hip/hip_fp16.h>

#define H 64
#define CBS 512           // nodes per coarse bucket
#define CB_BITS 9
#define TILE 4096         // edges per partition tile (R5: halved for 2x blocks)
#define CAP 9216          // slab capacity per bucket
#define NSTAT 64          // BN-stats replicas (contention spreading)
#define RPK_BLKS 53       // ceil(13322/256) repack blocks

typedef _Float16 f16;
typedef __attribute__((ext_vector_type(8))) _Float16 v8h;
typedef __attribute__((ext_vector_type(4))) float v4f;

// ---------------------------------------------------------------------------
// Tiny init: seed slab cursors + zero replicated BN stats.
// ---------------------------------------------------------------------------
__global__ __launch_bounds__(256)
void init_kernel(int* __restrict__ gcursor, float* __restrict__ statsR, int CB) {
    int t = threadIdx.x;
    if (t < CB) gcursor[t * 16] = t * CAP;
    for (int i = t; i < NSTAT * 128; i += 256) statsR[i] = 0.f;
}

// ---------------------------------------------------------------------------
// FRONT: one grid, three independent block ranges.
//   [0, ntiles)         : LDS-staged multi-split edge partition (TILE=4096)
//   [ntiles, +53)       : weight repack + folded head
//   [ntiles+53, ...)    : x -> fp16 conversion (streaming)
// ---------------------------------------------------------------------------
__global__ __launch_bounds__(256)
void front_kernel(const int* __restrict__ ei, int* __restrict__ gcursor,
                  int* __restrict__ pairs, int E, int N, int CB, int ntiles,
                  const float* __restrict__ x, f16* __restrict__ xh, int total4,
                  const float* __restrict__ W1a, const float* __restrict__ W1b,
                  const float* __restrict__ W2a, const float* __restrict__ W2b,
                  const float* __restrict__ B2b, const float* __restrict__ LW,
                  const float* __restrict__ LB,
                  f16* __restrict__ pk1a, f16* __restrict__ pk1b,
                  f16* __restrict__ pk2a, f16* __restrict__ pkf,
                  float* __restrict__ bf) {
    __shared__ int sd[256];
    __shared__ int excl[256];
    __shared__ int gbase[256];
    __shared__ int lcur[256];
    __shared__ int stage[TILE];
    __shared__ unsigned char bin8[TILE];
    int b = blockIdx.x;
    int t = threadIdx.x;

    if (b < ntiles) {
        int base = b * TILE;
        int cnt = min(TILE, E - base);
        sd[t] = 0;
        __syncthreads();
        for (int i = t; i < cnt; i += 256) {
            int s = ei[base + i];
            int d = ei[E + base + i];
            if ((unsigned)s < (unsigned)N && (unsigned)d < (unsigned)N)
                atomicAdd(&sd[d >> CB_BITS], 1);
        }
        __syncthreads();
        int v = sd[t];
        __syncthreads();
        for (int off = 1; off < 256; off <<= 1) {
            int add = (t >= off) ? sd[t - off] : 0;
            __syncthreads();
            sd[t] += add;
            __syncthreads();
        }
        int ex = sd[t] - v;
        excl[t] = ex;
        lcur[t] = ex;
        if (t < CB && v > 0) gbase[t] = atomicAdd(&gcursor[t * 16], v);
        int tot = sd[255];
        __syncthreads();
        for (int i = t; i < cnt; i += 256) {
            int s = ei[base + i];
            int d = ei[E + base + i];
            if ((unsigned)s < (unsigned)N && (unsigned)d < (unsigned)N) {
                int cb = d >> CB_BITS;
                int pos = atomicAdd(&lcur[cb], 1);
                stage[pos] = s | ((d & (CBS - 1)) << 17);
                bin8[pos] = (unsigned char)cb;
            }
        }
        __syncthreads();
        for (int i = t; i < tot; i += 256) {
            int b8 = bin8[i];
            pairs[gbase[b8] + (i - excl[b8])] = stage[i];
        }
        return;
    }
    b -= ntiles;
    if (b < RPK_BLKS) {
        int tt = b * 256 + t;
        if (tt < 12288) {
            int m = tt >> 12;
            int e = tt & 4095;
            int j = e & 7, lane = (e >> 3) & 63, ks = (e >> 9) & 1, nt = e >> 10;
            int row = ks * 32 + ((lane >> 4) & 3) * 8 + j;
            int col = nt * 16 + (lane & 15);
            const float* W = (m == 0) ? W1a : (m == 1) ? W1b : W2a;
            f16* P = (m == 0) ? pk1a : (m == 1) ? pk1b : pk2a;
            P[e] = (f16)W[row * 64 + col];
        } else if (tt < 13312) {
            int e = tt - 12288;
            int j = e & 7, lane = (e >> 3) & 63, ks = e >> 9;
            int row = ks * 32 + ((lane >> 4) & 3) * 8 + j;
            int col = lane & 15;
            float a = 0.f;
            if (col < 10)
                for (int m = 0; m < H; ++m) a = fmaf(W2b[row * 64 + m], LW[m * 10 + col], a);
            pkf[e] = (f16)a;
        } else if (tt < 13322) {
            int c = tt - 13312;
            float a = LB[c];
            for (int m = 0; m < H; ++m) a = fmaf(B2b[m], LW[m * 10 + c], a);
            bf[c] = a;
        }
        return;
    }
    b -= RPK_BLKS;
    int i = b * 256 + t;
    if (i >= total4) return;
    float4 v = ((const float4*)x)[i];
    f16 h0 = (f16)v.x, h1 = (f16)v.y, h2 = (f16)v.z, h3 = (f16)v.w;
    ushort4 pk;
    pk.x = *(unsigned short*)&h0; pk.y = *(unsigned short*)&h1;
    pk.z = *(unsigned short*)&h2; pk.w = *(unsigned short*)&h3;
    ((ushort4*)xh)[i] = pk;
}

// ---------------------------------------------------------------------------
// bucket CSR with inline bucket-prefix (R3-proven).
// ---------------------------------------------------------------------------
__global__ __launch_bounds__(256)
void bucket_csr_kernel(const int* __restrict__ pairs, const int* __restrict__ gcursor,
                       int* __restrict__ ebuf, int* __restrict__ rowptr, int N, int CB) {
    __shared__ int hist[CBS];
    __shared__ int cur[CBS];
    __shared__ int sd[256];
    __shared__ int carry_s;
    int b = blockIdx.x;
    int t = threadIdx.x;
    int c_t = (t < CB) ? (gcursor[t * 16] - t * CAP) : 0;
    sd[t] = c_t; __syncthreads();
    for (int off = 1; off < 256; off <<= 1) {
        int add = (t >= off) ? sd[t - off] : 0;
        __syncthreads();
        sd[t] += add;
        __syncthreads();
    }
    int cnt = gcursor[b * 16] - b * CAP;
    int gb = sd[b] - cnt;
    if (b == 0 && t == 0) rowptr[N] = sd[255];
    __syncthreads();

    int pb = b * CAP;
    for (int i = t; i < CBS; i += 256) hist[i] = 0;
    if (t == 0) carry_s = 0;
    __syncthreads();
    for (int i = t; i < cnt; i += 256)
        atomicAdd(&hist[(pairs[pb + i] >> 17) & (CBS - 1)], 1);
    __syncthreads();
    for (int start = 0; start < CBS; start += 256) {
        int v = hist[start + t];
        sd[t] = v; __syncthreads();
        for (int off = 1; off < 256; off <<= 1) {
            int add = (t >= off) ? sd[t - off] : 0;
            __syncthreads();
            sd[t] += add;
            __syncthreads();
        }
        int ex = sd[t] - v + carry_s;
        cur[start + t] = ex;
        int node = b * CBS + start + t;
        if (node < N) rowptr[node] = gb + ex;
        __syncthreads();
        if (t == 0) carry_s += sd[255];
        __syncthreads();
    }
    for (int i = t; i < cnt; i += 256) {
        int p = pairs[pb + i];
        int pos = atomicAdd(&cur[(p >> 17) & (CBS - 1)], 1);
        ebuf[gb + pos] = p & 0x1FFFF;
    }
}

// ---------------------------------------------------------------------------
// Layer-1 gather: 8 nodes/wave, 8 lanes/row, 16B/lane, 2-stage idx prefetch
// (issue chunk k+1's index loads before consuming chunk k's rows so index
// latency hides under row-gather + accumulate).
// ---------------------------------------------------------------------------
__global__ __launch_bounds__(256)
void gather1_kernel(const f16* __restrict__ xh, const int* __restrict__ rowptr,
                    const int* __restrict__ ebuf, f16* __restrict__ bufA,
                    int N, int Em1) {
    int wid = (int)(((long long)blockIdx.x * blockDim.x + threadIdx.x) >> 6);
    int lane = threadIdx.x & 63;
    int g = lane >> 3, fl = lane & 7;
    int node = wid * 8 + g;
    bool vn = node < N;
    int p0 = 0, deg = 0;
    if (vn) {
        p0 = rowptr[node];
        deg = rowptr[node + 1] - p0;
    }
    float a[8];
    {
        v8h s = {};
        if (vn) s = *(const v8h*)(xh + ((size_t)node << 6) + fl * 8);
#pragma unroll
        for (int j = 0; j < 8; ++j) a[j] = (float)s[j];
    }
    int k = 0;
    if (deg >= 16) {
        int idxA[8];
#pragma unroll
        for (int q = 0; q < 8; ++q) idxA[q] = ebuf[p0 + q];
        for (; k + 16 <= deg; k += 8) {
            int idxB[8];
#pragma unroll
            for (int q = 0; q < 8; ++q) idxB[q] = ebuf[p0 + k + 8 + q];
#pragma unroll
            for (int q = 0; q < 8; ++q) {
                v8h v = *(const v8h*)(xh + ((size_t)idxA[q] << 6) + fl * 8);
#pragma unroll
                for (int j = 0; j < 8; ++j) a[j] += (float)v[j];
            }
#pragma unroll
            for (int q = 0; q < 8; ++q) idxA[q] = idxB[q];
        }
#pragma unroll
        for (int q = 0; q < 8; ++q) {
            v8h v = *(const v8h*)(xh + ((size_t)idxA[q] << 6) + fl * 8);
#pragma unroll
            for (int j = 0; j < 8; ++j) a[j] += (float)v[j];
        }
        k += 8;
    } else if (deg >= 8) {
        int idxA[8];
#pragma unroll
        for (int q = 0; q < 8; ++q) idxA[q] = ebuf[p0 + q];
#pragma unroll
        for (int q = 0; q < 8; ++q) {
            v8h v = *(const v8h*)(xh + ((size_t)idxA[q] << 6) + fl * 8);
#pragma unroll
            for (int j = 0; j < 8; ++j) a[j] += (float)v[j];
        }
        k = 8;
    }
    if (k < deg) {
        int idx[8];
#pragma unroll
        for (int q = 0; q < 8; ++q) idx[q] = ebuf[min(p0 + k + q, Em1)];
#pragma unroll
        for (int q = 0; q < 8; ++q) {
            if (k + q < deg) {
                v8h v = *(const v8h*)(xh + ((size_t)idx[q] << 6) + fl * 8);
#pragma unroll
                for (int j = 0; j < 8; ++j) a[j] += (float)v[j];
            }
        }
    }
    if (vn) {
        v8h o;
#pragma unroll
        for (int j = 0; j < 8; ++j) o[j] = (f16)a[j];
        *(v8h*)(bufA + ((size_t)node << 6) + fl * 8) = o;
    }
}

// ---------------------------------------------------------------------------
// Layer-2 gather with INLINE BN-finalize (statsR -> scale/shift in LDS per
// block; removes the bn_finalize dispatch) + self term + folded BN epilogue.
// Same 2-stage idx prefetch as gather1.
// ---------------------------------------------------------------------------
__global__ __launch_bounds__(256)
void gather2_kernel(const f16* __restrict__ h1p, const float* __restrict__ statsR,
                    const float* __restrict__ gamma, const float* __restrict__ beta,
                    const int* __restrict__ rowptr, const int* __restrict__ ebuf,
                    f16* __restrict__ bufC, int N, int Em1, float n) {
    __shared__ float s_scale[64];
    __shared__ float s_shift[64];
    int t = threadIdx.x;
    if (t < 64) {
        float s = 0.f, s2 = 0.f;
#pragma unroll 8
        for (int r = 0; r < NSTAT; ++r) {
            s  += statsR[r * 128 + t];
            s2 += statsR[r * 128 + 64 + t];
        }
        float mean = s / n;
        float var = fmaxf(s2 / n - mean * mean, 0.f);   // biased, matches jnp.var
        float sc = gamma[t] * rsqrtf(var + 1e-5f);
        s_scale[t] = sc;
        s_shift[t] = beta[t] - mean * sc;
    }
    __syncthreads();

    int wid = (int)(((long long)blockIdx.x * blockDim.x + t) >> 6);
    int lane = t & 63;
    int g = lane >> 3, fl = lane & 7;
    int node = wid * 8 + g;
    bool vn = node < N;
    int p0 = 0, deg = 0;
    if (vn) {
        p0 = rowptr[node];
        deg = rowptr[node + 1] - p0;
    }
    float a[8];
    {
        v8h s = {};
        if (vn) s = *(const v8h*)(h1p + ((size_t)node << 6) + fl * 8);
#pragma unroll
        for (int j = 0; j < 8; ++j) a[j] = (float)s[j];
    }
    int k = 0;
    if (deg >= 16) {
        int idxA[8];
#pragma unroll
        for (int q = 0; q < 8; ++q) idxA[q] = ebuf[p0 + q];
        for (; k + 16 <= deg; k += 8) {
            int idxB[8];
#pragma unroll
            for (int q = 0; q < 8; ++q) idxB[q] = ebuf[p0 + k + 8 + q];
#pragma unroll
            for (int q = 0; q < 8; ++q) {
                v8h v = *(const v8h*)(h1p + ((size_t)idxA[q] << 6) + fl * 8);
#pragma unroll
                for (int j = 0; j < 8; ++j) a[j] += (float)v[j];
            }
#pragma unroll
            for (int q = 0; q < 8; ++q) idxA[q] = idxB[q];
        }
#pragma unroll
        for (int q = 0; q < 8; ++q) {
            v8h v = *(const v8h*)(h1p + ((size_t)idxA[q] << 6) + fl * 8);
#pragma unroll
            for (int j = 0; j < 8; ++j) a[j] += (float)v[j];
        }
        k += 8;
    } else if (deg >= 8) {
        int idxA[8];
#pragma unroll
        for (int q = 0; q < 8; ++q) idxA[q] = ebuf[p0 + q];
#pragma unroll
        for (int q = 0; q < 8; ++q) {
            v8h v = *(const v8h*)(h1p + ((size_t)idxA[q] << 6) + fl * 8);
#pragma unroll
            for (int j = 0; j < 8; ++j) a[j] += (float)v[j];
        }
        k = 8;
    }
    if (k < deg) {
        int idx[8];
#pragma unroll
        for (int q = 0; q < 8; ++q) idx[q] = ebuf[min(p0 + k + q, Em1)];
#pragma unroll
        for (int q = 0; q < 8; ++q) {
            if (k + q < deg) {
                v8h v = *(const v8h*)(h1p + ((size_t)idx[q] << 6) + fl * 8);
#pragma unroll
                for (int j = 0; j < 8; ++j) a[j] += (float)v[j];
            }
        }
    }
    if (vn) {
        float degp1 = (float)(deg + 1);
        v8h o;
#pragma unroll
        for (int j = 0; j < 8; ++j)
            o[j] = (f16)(a[j] * s_scale[fl * 8 + j] + degp1 * s_shift[fl * 8 + j]);
        *(v8h*)(bufC + ((size_t)node << 6) + fl * 8) = o;
    }
}

// ---------------------------------------------------------------------------
// MFMA MLP layer 1 + fused BN stats into replicated accumulators (R2-proven).
// ---------------------------------------------------------------------------
__global__ __launch_bounds__(256)
void mlp1_kernel(const f16* __restrict__ bufA, f16* __restrict__ h1p,
                 const f16* __restrict__ pk1a, const f16* __restrict__ pk1b,
                 const float* __restrict__ B1a, const float* __restrict__ B1b,
                 float* __restrict__ statsR, int N) {
    __shared__ f16 Su[4][16 * 72];
    __shared__ f16 Sh[4][16 * 72];
    __shared__ float red[2][4][64];
    int t = threadIdx.x, wv = t >> 6, lane = t & 63;
    int quad = lane >> 4, r16 = lane & 15;
    int node0 = blockIdx.x * 64 + wv * 16;
    int nodeA = node0 + r16;

    v8h a0 = {}, a1 = {};
    if (nodeA < N) {
        a0 = *(const v8h*)(bufA + (size_t)nodeA * 64 + quad * 8);
        a1 = *(const v8h*)(bufA + (size_t)nodeA * 64 + 32 + quad * 8);
    }
#pragma unroll
    for (int nt = 0; nt < 4; ++nt) {
        v8h b0 = *(const v8h*)(pk1a + (((nt * 2 + 0) * 64 + lane) << 3));
        v8h b1 = *(const v8h*)(pk1a + (((nt * 2 + 1) * 64 + lane) << 3));
        v4f c = {0.f, 0.f, 0.f, 0.f};
        c = __builtin_amdgcn_mfma_f32_16x16x32_f16(a0, b0, c, 0, 0, 0);
        c = __builtin_amdgcn_mfma_f32_16x16x32_f16(a1, b1, c, 0, 0, 0);
        float bias = B1a[nt * 16 + r16];
#pragma unroll
        for (int reg = 0; reg < 4; ++reg)
            Su[wv][(quad * 4 + reg) * 72 + nt * 16 + r16] = (f16)fmaxf(c[reg] + bias, 0.f);
    }
    __syncthreads();
    v8h u0 = *(const v8h*)(&Su[wv][r16 * 72 + quad * 8]);
    v8h u1 = *(const v8h*)(&Su[wv][r16 * 72 + 32 + quad * 8]);
#pragma unroll
    for (int nt = 0; nt < 4; ++nt) {
        v8h b0 = *(const v8h*)(pk1b + (((nt * 2 + 0) * 64 + lane) << 3));
        v8h b1 = *(const v8h*)(pk1b + (((nt * 2 + 1) * 64 + lane) << 3));
        v4f c = {0.f, 0.f, 0.f, 0.f};
        c = __builtin_amdgcn_mfma_f32_16x16x32_f16(u0, b0, c, 0, 0, 0);
        c = __builtin_amdgcn_mfma_f32_16x16x32_f16(u1, b1, c, 0, 0, 0);
        float bias = B1b[nt * 16 + r16];
#pragma unroll
        for (int reg = 0; reg < 4; ++reg) {
            int row = quad * 4 + reg;
            bool valid = (node0 + row) < N;
            Sh[wv][row * 72 + nt * 16 + r16] = valid ? (f16)(c[reg] + bias) : (f16)0;
        }
    }
    __syncthreads();
    for (int i = lane; i < 1024; i += 64) {
        int row = i >> 6, col = i & 63;
        int node = node0 + row;
        if (node < N) h1p[(size_t)node * 64 + col] = Sh[wv][row * 72 + col];
    }
    float s = 0.f, s2 = 0.f;
#pragma unroll
    for (int row = 0; row < 16; ++row) {
        float v = (float)Sh[wv][row * 72 + lane];
        s += v;
        s2 = fmaf(v, v, s2);
    }
    red[0][wv][lane] = s;
    red[1][wv][lane] = s2;
    __syncthreads();
    if (wv == 0) {
        float ts  = (red[0][0][lane] + red[0][1][lane]) + (red[0][2][lane] + red[0][3][lane]);
        float ts2 = (red[1][0][lane] + red[1][1][lane]) + (red[1][2][lane] + red[1][3][lane]);
        float* st = statsR + (size_t)(blockIdx.x & (NSTAT - 1)) * 128;
        unsafeAtomicAdd(&st[lane], ts);
        unsafeAtomicAdd(&st[64 + lane], ts2);
    }
}

// ---------------------------------------------------------------------------
// MFMA MLP layer 2 + folded head (R2-proven).
// ---------------------------------------------------------------------------
__global__ __launch_bounds__(256)
void mlp2_kernel(const f16* __restrict__ bufC,
                 const f16* __restrict__ pk2a, const f16* __restrict__ pkf,
                 const float* __restrict__ B2a, const float* __restrict__ bf,
                 float* __restrict__ out, int N) {
    __shared__ f16 Su[4][16 * 72];
    int t = threadIdx.x, wv = t >> 6, lane = t & 63;
    int quad = lane >> 4, r16 = lane & 15;
    int node0 = blockIdx.x * 64 + wv * 16;
    int nodeA = node0 + r16;

    v8h a0 = {}, a1 = {};
    if (nodeA < N) {
        a0 = *(const v8h*)(bufC + (size_t)nodeA * 64 + quad * 8);
        a1 = *(const v8h*)(bufC + (size_t)nodeA * 64 + 32 + quad * 8);
    }
#pragma unroll
    for (int nt = 0; nt < 4; ++nt) {
        v8h b0 = *(const v8h*)(pk2a + (((nt * 2 + 0) * 64 + lane) << 3));
        v8h b1 = *(const v8h*)(pk2a + (((nt * 2 + 1) * 64 + lane) << 3));
        v4f c = {0.f, 0.f, 0.f, 0.f};
        c = __builtin_amdgcn_mfma_f32_16x16x32_f16(a0, b0, c, 0, 0, 0);
        c = __builtin_amdgcn_mfma_f32_16x16x32_f16(a1, b1, c, 0, 0, 0);
        float bias = B2a[nt * 16 + r16];
#pragma unroll
        for (int reg = 0; reg < 4; ++reg)
            Su[wv][(quad * 4 + reg) * 72 + nt * 16 + r16] = (f16)fmaxf(c[reg] + bias, 0.f);
    }
    __syncthreads();
    v8h u0 = *(const v8h*)(&Su[wv][r16 * 72 + quad * 8]);
    v8h u1 = *(const v8h*)(&Su[wv][r16 * 72 + 32 + quad * 8]);
    v8h b0 = *(const v8h*)(pkf + ((0 * 64 + lane) << 3));
    v8h b1 = *(const v8h*)(pkf + ((1 * 64 + lane) << 3));
    v4f c = {0.f, 0.f, 0.f, 0.f};
    c = __builtin_amdgcn_mfma_f32_16x16x32_f16(u0, b0, c, 0, 0, 0);
    c = __builtin_amdgcn_mfma_f32_16x16x32_f16(u1, b1, c, 0, 0, 0);
    if (r16 < 10) {
        float bias = bf[r16];
#pragma unroll
        for (int reg = 0; reg < 4; ++reg) {
            int node = node0 + quad * 4 + reg;
            if (node < N) out[(size_t)node * 10 + r16] = c[reg] + bias;
        }
    }
}

extern "C" void kernel_launch(void* const* d_in, const int* in_sizes, int n_in,
                              void* d_out, int out_size, void* d_ws, size_t ws_size,
                              hipStream_t stream) {
    const float* x    = (const float*)d_in[0];
    const int*   ei   = (const int*)d_in[1];
    const float* w1a  = (const float*)d_in[2];
    const float* b1a  = (const float*)d_in[3];
    const float* w1b  = (const float*)d_in[4];
    const float* b1b  = (const float*)d_in[5];
    const float* bng  = (const float*)d_in[6];
    const float* bnb  = (const float*)d_in[7];
    const float* w2a  = (const float*)d_in[8];
    const float* b2a  = (const float*)d_in[9];
    const float* w2b  = (const float*)d_in[10];
    const float* b2b  = (const float*)d_in[11];
    const float* linw = (const float*)d_in[12];
    const float* linb = (const float*)d_in[13];

    int N = in_sizes[0] / H;       // 100000
    int E = in_sizes[1] / 2;       // 1600000
    int CB = (N + CBS - 1) / CBS;  // 196 coarse buckets

    // ---- workspace layout ----
    size_t NH = (size_t)N * H;
    char*  wsb    = (char*)d_ws;
    f16*   xh     = (f16*)wsb;                           // NH fp16
    f16*   bufA   = (f16*)(wsb + NH * 2);                // NH fp16 (agg1 -> h1p in place)
    f16*   bufC   = (f16*)(wsb + NH * 4);                // NH fp16
    float* stats  = (float*)(wsb + NH * 6);              // 128 (legacy, unused)
    float* scale  = stats + 128;                         // 64 (legacy, unused)
    float* shiftv = stats + 192;                         // 64 (legacy, unused)
    float* bf     = stats + 256;                         // 16
    f16*   pk1a   = (f16*)(bf + 16);                     // 4096 (16B-aligned)
    f16*   pk1b   = pk1a + 4096;
    f16*   pk2a   = pk1b + 4096;
    f16*   pkf    = pk2a + 4096;                         // 1024
    int*   gcursor= (int*)(pkf + 1024);                  // 256*16
    int*   rowptr = gcursor + 256 * 16;                  // N+1
    int*   ebuf   = rowptr + (N + 1);                    // E
    int*   pairs  = ebuf + E;                            // CB*CAP slab
    float* statsR = (float*)(pairs + (size_t)CB * CAP);  // NSTAT*128 (own slot)

    int ntiles = (E + TILE - 1) / TILE;
    int total4 = (int)(NH / 4);
    int cvtblocks = (total4 + 255) / 256;
    int mblocks = (N + 63) / 64;
    int nwaves = (N + 7) / 8;
    int gblocks = (int)(((long long)nwaves * 64 + 255) / 256);

    init_kernel<<<1, 256, 0, stream>>>(gcursor, statsR, CB);
    front_kernel<<<ntiles + RPK_BLKS + cvtblocks, 256, 0, stream>>>(
        ei, gcursor, pairs, E, N, CB, ntiles,
        x, xh, total4,
        w1a, w1b, w2a, w2b, b2b, linw, linb,
        pk1a, pk1b, pk2a, pkf, bf);
    bucket_csr_kernel<<<CB, 256, 0, stream>>>(pairs, gcursor, ebuf, rowptr, N, CB);

    gather1_kernel<<<gblocks, 256, 0, stream>>>(xh, rowptr, ebuf, bufA, N, E - 1);
    mlp1_kernel<<<mblocks, 256, 0, stream>>>(bufA, bufA, pk1a, pk1b, b1a, b1b, statsR, N);

    gather2_kernel<<<gblocks, 256, 0, stream>>>(
        bufA, statsR, bng, bnb, rowptr, ebuf, bufC, N, E - 1, (float)N);
    mlp2_kernel<<<mblocks, 256, 0, stream>>>(bufC, pk2a, pkf, b2a, bf, (float*)d_out, N);
}